// Round 12
// baseline (324.663 us; speedup 1.0000x reference)
//
#include <hip/hip_runtime.h>
#include <math.h>

#define BB 8
#define NT 1025
#define CD 512
#define NH 8
#define DHD 64
#define HW 1024
#define FWD 17
#define MTOK 8200
#define MPAD 8320
#define QKS 1536

typedef __attribute__((ext_vector_type(8))) short short8;
typedef __attribute__((ext_vector_type(4))) float f32x4;
typedef __attribute__((ext_vector_type(16))) float f32x16;
typedef __attribute__((ext_vector_type(4))) unsigned u32x4;

__device__ __forceinline__ float gelu_exact(float x){
  return 0.5f * x * (1.0f + erff(x * 0.70710678118654752f));
}

__device__ __forceinline__ short f2bf(float f){
  unsigned u = __float_as_uint(f);
  unsigned r = (u + 0x7FFFu + ((u >> 16) & 1u)) >> 16;
  return (short)r;
}

__device__ __forceinline__ float bf2f(short s){
  unsigned u = ((unsigned)(unsigned short)s) << 16;
  return __uint_as_float(u);
}

__device__ __forceinline__ unsigned cvt_pk_bf16(float lo, float hi){
  unsigned r;
  asm volatile("v_cvt_pk_bf16_f32 %0, %1, %2" : "=v"(r) : "v"(lo), "v"(hi));
  return r;
}

// direct global->LDS DMA, 16B per lane; LDS dest is wave-uniform base + lane*16
typedef const __attribute__((address_space(1))) unsigned GASu;
typedef __attribute__((address_space(3))) unsigned LASu;
__device__ __forceinline__ void gload16(const void* g, void* l){
  __builtin_amdgcn_global_load_lds((GASu*)g, (LASu*)l, 16, 0, 0);
}

// bijective XCD swizzle (m204)
__device__ __forceinline__ int xcd_logical(int phys, int n){
  int xcd = phys & 7, slot = phys >> 3;
  int q = n >> 3, r = n & 7;
  return xcd*q + (xcd < r ? xcd : r) + slot;
}

// ---------------- ALL weight transposes+convert in ONE kernel ----------------
__global__ __launch_bounds__(256) void wconv_all(
    const float* __restrict__ Wq, const float* __restrict__ Wk, const float* __restrict__ Wv,
    const float* __restrict__ pw, const float* __restrict__ frpw,
    const float* __restrict__ gW1, const float* __restrict__ Wp,
    short* __restrict__ wqkvt, short* __restrict__ pwt, short* __restrict__ frpwt,
    short* __restrict__ gw1t, short* __restrict__ wpt)
{
  const int t = blockIdx.x;
  const float* W; short* Wt; int K, N, idx; float scale = 1.0f;
  if      (t < 256) { W = Wq;   Wt = wqkvt;            K=512;  N=512; idx=t;       scale=0.125f; }
  else if (t < 512) { W = Wk;   Wt = wqkvt+512*512;    K=512;  N=512; idx=t-256; }
  else if (t < 768) { W = Wv;   Wt = wqkvt+1024*512;   K=512;  N=512; idx=t-512; }
  else if (t < 1024){ W = pw;   Wt = pwt;              K=512;  N=512; idx=t-768; }
  else if (t < 1280){ W = frpw; Wt = frpwt;            K=512;  N=512; idx=t-1024; }
  else if (t < 1856){ W = gW1;  Wt = gw1t;             K=1536; N=384; idx=t-1280; }
  else              { W = Wp;   Wt = wpt;              K=512;  N=512; idx=t-1856; }
  const int ntn = N >> 5;
  const int n0 = (idx % ntn) << 5, k0 = (idx / ntn) << 5;
  __shared__ float tl[32][33];
  const int tx = threadIdx.x & 31, ty = threadIdx.x >> 5;
  #pragma unroll
  for (int i = 0; i < 32; i += 8)
    tl[ty+i][tx] = W[(size_t)(k0+ty+i)*N + n0+tx];
  __syncthreads();
  #pragma unroll
  for (int i = 0; i < 32; i += 8)
    Wt[(size_t)(n0+ty+i)*K + k0+tx] = f2bf(tl[tx][ty+i] * scale);
}

// ---------------- x fp32 -> bf16, rows >= MTOK zeroed ----------------
__global__ __launch_bounds__(256) void x2bf(const float* __restrict__ x, short* __restrict__ xb)
{
  size_t i = ((size_t)blockIdx.x*256 + threadIdx.x) * 8;
  if (i >= (size_t)MPAD*CD) return;
  size_t row = i >> 9;
  short8 o;
  if (row < MTOK){
    #pragma unroll
    for (int j = 0; j < 8; j++) o[j] = f2bf(x[i+j]);
  } else {
    #pragma unroll
    for (int j = 0; j < 8; j++) o[j] = 0;
  }
  *(short8*)(xb + i) = o;
}

// ======== 2-phase GEMM core with global_load_lds staging =====================
// 128x64 tile, BK=64, 4 waves, double-buffered LDS, linear dest + src-swizzle.

#define GEMM_DECL                                                          \
  __shared__ short As[2][128*64];                                          \
  __shared__ short Bs[2][64*64];                                           \
  const int tid = threadIdx.x;                                             \
  const int lane = tid & 63, wv = tid >> 6;                                \
  const int lc = lane & 15, lg = lane >> 4;                                \
  f32x4 acc[2][4];                                                         \
  _Pragma("unroll")                                                        \
  for (int rt=0;rt<2;rt++)                                                 \
    _Pragma("unroll")                                                      \
    for (int ct=0;ct<4;ct++) acc[rt][ct] = (f32x4){0.f,0.f,0.f,0.f};

// issue 4 A-waveloads (8 rows each) + 2 B-waveloads per wave into buf
#define GEMM_ISSUE(Aptr, Ka, k0a, Bptr, Kb, k0b, buf)                      \
  _Pragma("unroll")                                                        \
  for (int p = 0; p < 4; p++){                                             \
    int r0 = wv*32 + p*8;                                                  \
    int r = r0 + (lane>>3), s = lane & 7;                                  \
    gload16((Aptr) + (size_t)(row0 + r)*(Ka) + (k0a) + ((s ^ (r&7))*8),    \
            &As[buf][r0*64]);                                              \
  }                                                                        \
  _Pragma("unroll")                                                        \
  for (int p = 0; p < 2; p++){                                             \
    int r0 = wv*16 + p*8;                                                  \
    int r = r0 + (lane>>3), s = lane & 7;                                  \
    gload16((Bptr) + (size_t)(col0 + r)*(Kb) + (k0b) + ((s ^ (r&7))*8),    \
            &Bs[buf][r0*64]);                                              \
  }

#define GEMM_COMPUTE(buf)                                                  \
  _Pragma("unroll")                                                        \
  for (int ks = 0; ks < 2; ks++){                                          \
    short8 af[2], bfr[4];                                                  \
    _Pragma("unroll")                                                      \
    for (int rt = 0; rt < 2; rt++){                                        \
      int r = wv*32 + rt*16 + lc;                                          \
      af[rt] = *(const short8*)&As[buf][r*64 + (((ks*4+lg) ^ (r & 7))*8)]; \
    }                                                                      \
    _Pragma("unroll")                                                      \
    for (int ct = 0; ct < 4; ct++){                                        \
      int r = ct*16 + lc;                                                  \
      bfr[ct] = *(const short8*)&Bs[buf][r*64 + (((ks*4+lg) ^ (r & 7))*8)];\
    }                                                                      \
    _Pragma("unroll")                                                      \
    for (int rt = 0; rt < 2; rt++)                                         \
      _Pragma("unroll")                                                    \
      for (int ct = 0; ct < 4; ct++)                                       \
        acc[rt][ct] = __builtin_amdgcn_mfma_f32_16x16x32_bf16(af[rt], bfr[ct], acc[rt][ct], 0,0,0); \
  }

// ---------------- generic GEMM (QKV / final), XCD-swizzled 1D grid ----------
__global__ __launch_bounds__(256) void gemm_bf16(
    const short* __restrict__ A, const short* __restrict__ Bt,
    const float* __restrict__ bias, void* __restrict__ Cm,
    int M, int N, int K, int flags)
{
  const int l = xcd_logical(blockIdx.x, gridDim.x);
  const int nx = N >> 6;
  const int row0 = (l / nx) * 128, col0 = (l % nx) * 64;
  GEMM_DECL;

  const int nk = K >> 6;
  GEMM_ISSUE(A, K, 0, Bt, K, 0, 0);
  __syncthreads();
  for (int kt = 0; kt < nk; kt++){
    const int cur = kt & 1;
    if (kt + 1 < nk){ GEMM_ISSUE(A, K, (kt+1)*64, Bt, K, (kt+1)*64, cur ^ 1); }
    GEMM_COMPUTE(cur);
    if (kt + 1 < nk) __syncthreads();
  }

  #pragma unroll
  for (int rt = 0; rt < 2; rt++)
    #pragma unroll
    for (int e = 0; e < 4; e++){
      int gr = row0 + wv*32 + rt*16 + lg*4 + e;
      if (gr >= M) continue;
      #pragma unroll
      for (int ct = 0; ct < 4; ct++){
        int gc = col0 + ct*16 + lc;
        float v = acc[rt][ct][e];
        if (flags & 1) v += bias[gc];
        if (flags & 2) v = gelu_exact(v);
        if (flags & 4) ((short*)Cm)[(size_t)gr*N + gc] = f2bf(v);
        else           ((float*)Cm)[(size_t)gr*N + gc] = v;
      }
    }
}

// ---------------- merged pointwise GEMMs (1024 blocks, XCD-swizzled) --------
__global__ __launch_bounds__(256) void gemm_pw2(
    const short* __restrict__ A0, const short* __restrict__ B0,
    const short* __restrict__ A1, const short* __restrict__ B1,
    short* __restrict__ C0, short* __restrict__ C1,
    float* __restrict__ totL, float* __restrict__ totF)
{
  const int l = xcd_logical(blockIdx.x, 1024);
  const int bx = l & 7;
  const int by = (l >> 3) & 63;
  const int br = l >> 9;
  const short* A  = br ? A1 : A0;
  const short* Bt = br ? B1 : B0;
  short* Cm       = br ? C1 : C0;
  float* tot      = br ? totF : totL;
  const int N = 512, K = 512;
  const int row0 = by * 128, col0 = bx * 64;
  GEMM_DECL;

  const int nk = 8;
  GEMM_ISSUE(A, K, 0, Bt, K, 0, 0);
  __syncthreads();
  for (int kt = 0; kt < nk; kt++){
    const int cur = kt & 1;
    if (kt + 1 < nk){ GEMM_ISSUE(A, K, (kt+1)*64, Bt, K, (kt+1)*64, cur ^ 1); }
    GEMM_COMPUTE(cur);
    if (kt + 1 < nk) __syncthreads();
  }

  float s1 = 0.f, s2 = 0.f;
  #pragma unroll
  for (int rt = 0; rt < 2; rt++)
    #pragma unroll
    for (int e = 0; e < 4; e++){
      int gr = row0 + wv*32 + rt*16 + lg*4 + e;
      #pragma unroll
      for (int ct = 0; ct < 4; ct++){
        int gc = col0 + ct*16 + lc;
        float v = acc[rt][ct][e];
        Cm[(size_t)gr*N + gc] = f2bf(v);
        s1 += v; s2 += v*v;
      }
    }
  #pragma unroll
  for (int o = 32; o > 0; o >>= 1){ s1 += __shfl_xor(s1, o); s2 += __shfl_xor(s2, o); }
  if (lane == 0){
    atomicAdd(&tot[(row0>>10)*2],   s1);
    atomicAdd(&tot[(row0>>10)*2+1], s2);
  }
}

// ---------------- gate GEMM (390 blocks, XCD-swizzled, 3-source A) ----------
__global__ __launch_bounds__(256) void gemm_gate(
    const short* __restrict__ A0, const short* __restrict__ A1, const short* __restrict__ A2,
    const short* __restrict__ Bt, const float* __restrict__ bias, short* __restrict__ Cm,
    int M)
{
  const int N = 384, K = 1536;
  const int l = xcd_logical(blockIdx.x, gridDim.x);
  const int row0 = (l / 6) * 128, col0 = (l % 6) * 64;
  GEMM_DECL;

  const int nk = 24;
  {
    const short* Asrc = A0;
    GEMM_ISSUE(Asrc, 512, 0, Bt, K, 0, 0);
  }
  __syncthreads();
  for (int kt = 0; kt < nk; kt++){
    const int cur = kt & 1;
    if (kt + 1 < nk){
      int k0 = (kt+1) * 64;
      const short* Asrc = (k0 < 512) ? A0 : (k0 < 1024 ? A1 : A2);
      const int kb = k0 & 511;
      GEMM_ISSUE(Asrc, 512, kb, Bt, K, k0, cur ^ 1);
    }
    GEMM_COMPUTE(cur);
    if (kt + 1 < nk) __syncthreads();
  }

  #pragma unroll
  for (int rt = 0; rt < 2; rt++)
    #pragma unroll
    for (int e = 0; e < 4; e++){
      int gr = row0 + wv*32 + rt*16 + lg*4 + e;
      if (gr >= M) continue;
      #pragma unroll
      for (int ct = 0; ct < 4; ct++){
        int gc = col0 + ct*16 + lc;
        float v = acc[rt][ct][e] + bias[gc];
        Cm[(size_t)gr*N + gc] = f2bf(gelu_exact(v));
      }
    }
}

// ---------------- Flash attention: 32x32 MFMA, swapped QK^T, in-reg softmax ---
__global__ __launch_bounds__(256) void attn_mfma32(
    const short* __restrict__ qkv, short* __restrict__ glob)
{
  const int bi = blockIdx.x;
  const int xcd = bi & 7;
  const int jj = bi >> 3;
  const int gq = jj / 9;
  const int qt = jj - gq*9;
  const int g  = xcd + 8*gq;
  const int h  = g & 7, b = g >> 3;

  const int tid = threadIdx.x;
  const int lane = tid & 63, wq = tid >> 6;
  const int q32 = lane & 31;
  const int hi  = lane >> 5;
  const int bN = b * NT;
  const int q0w = qt*128 + wq*32;

  __shared__ short Kl[2][64*64];
  __shared__ short Vl[2][64*64];

  short8 qf[4];
  {
    int qr = q0w + q32; if (qr > 1024) qr = 1024;
    const short* qp = qkv + (size_t)(bN + qr)*QKS + h*DHD + hi*8;
    qf[0] = *(const short8*)(qp);
    qf[1] = *(const short8*)(qp + 16);
    qf[2] = *(const short8*)(qp + 32);
    qf[3] = *(const short8*)(qp + 48);
  }

  f32x16 oA = {0.f,0.f,0.f,0.f,0.f,0.f,0.f,0.f,0.f,0.f,0.f,0.f,0.f,0.f,0.f,0.f};
  f32x16 oB = oA;
  float rs = 0.f;

  const int kc0 = tid;
  const int kc1 = tid + 256;
  const int vkey = tid & 63, vdg = tid >> 6;
  const short* kgbase = qkv + (size_t)bN*QKS + 512 + h*DHD;
  const short* vgbase = qkv + (size_t)bN*QKS + 1024 + h*DHD;

  short8 gk0, gk1, gv0, gv1;
  auto loadT = [&](int kt2){
    gk0 = *(const short8*)(kgbase + (size_t)(kt2*64 + (kc0>>3))*QKS + (kc0&7)*8);
    gk1 = *(const short8*)(kgbase + (size_t)(kt2*64 + (kc1>>3))*QKS + (kc1&7)*8);
    gv0 = *(const short8*)(vgbase + (size_t)(kt2*64 + vkey)*QKS + vdg*16);
    gv1 = *(const short8*)(vgbase + (size_t)(kt2*64 + vkey)*QKS + vdg*16 + 8);
  };
  auto writeT = [&](int buf){
    { int r = kc0>>3, sl = kc0&7;
      *(short8*)&Kl[buf][r*64 + (((sl) ^ (r&7))*8)] = gk0; }
    { int r = kc1>>3, sl = kc1&7;
      *(short8*)&Kl[buf][r*64 + (((sl) ^ (r&7))*8)] = gk1; }
    #pragma unroll
    for (int i2 = 0; i2 < 8; i2++){
      int d0 = vdg*16 + i2, d1 = vdg*16 + 8 + i2;
      Vl[buf][d0*64 + (((vkey>>3) ^ (d0&7))*8) + (vkey&7)] = gv0[i2];
      Vl[buf][d1*64 + (((vkey>>3) ^ (d1&7))*8) + (vkey&7)] = gv1[i2];
    }
  };

  loadT(0);
  writeT(0);
  __syncthreads();

  for (int kt = 0; kt < 17; kt++){
    const int cur = kt & 1;
    if (kt < 16) loadT(kt+1);

    #pragma unroll
    for (int ks = 0; ks < 2; ks++){
      f32x16 s = {0.f,0.f,0.f,0.f,0.f,0.f,0.f,0.f,0.f,0.f,0.f,0.f,0.f,0.f,0.f,0.f};
      const int krow = ks*32 + q32;
      const int kbase = krow*64;
      const int kx = q32 & 7;
      __builtin_amdgcn_s_setprio(1);
      #pragma unroll
      for (int kk = 0; kk < 4; kk++){
        short8 af = *(const short8*)&Kl[cur][kbase + (((2*kk+hi) ^ kx)*8)];
        s = __builtin_amdgcn_mfma_f32_32x32x16_bf16(af, qf[kk], s, 0,0,0);
      }
      __builtin_amdgcn_s_setprio(0);
      float p[16];
      if (kt == 16){
        #pragma unroll
        for (int e = 0; e < 16; e++){
          bool valid = (ks == 0) && (e == 0) && (hi == 0);
          p[e] = valid ? __expf(s[e]) : 0.f;
        }
      } else {
        #pragma unroll
        for (int e = 0; e < 16; e++) p[e] = __expf(s[e]);
      }
      #pragma unroll
      for (int e = 0; e < 16; e++) rs += p[e];
      unsigned pk[4][2];
      #pragma unroll
      for (int g2 = 0; g2 < 4; g2++){
        pk[g2][0] = cvt_pk_bf16(p[4*g2+0], p[4*g2+1]);
        pk[g2][1] = cvt_pk_bf16(p[4*g2+2], p[4*g2+3]);
      }
      #pragma unroll
      for (int kc = 0; kc < 2; kc++){
        unsigned e00 = pk[2*kc][0],   e01 = pk[2*kc][1];
        unsigned e10 = pk[2*kc+1][0], e11 = pk[2*kc+1][1];
        unsigned t00 = (unsigned)__shfl_xor((int)e00, 32);
        unsigned t01 = (unsigned)__shfl_xor((int)e01, 32);
        unsigned t10 = (unsigned)__shfl_xor((int)e10, 32);
        unsigned t11 = (unsigned)__shfl_xor((int)e11, 32);
        u32x4 pu;
        pu[0] = hi ? t10 : e00;
        pu[1] = hi ? t11 : e01;
        pu[2] = hi ? e10 : t00;
        pu[3] = hi ? e11 : t01;
        short8 pa = *(short8*)&pu;
        const int vsl = 4*ks + 2*kc + hi;
        __builtin_amdgcn_s_setprio(1);
        {
          short8 vf0 = *(const short8*)&Vl[cur][(q32)*64      + ((vsl ^ kx)*8)];
          oA = __builtin_amdgcn_mfma_f32_32x32x16_bf16(pa, vf0, oA, 0,0,0);
          short8 vf1 = *(const short8*)&Vl[cur][(32+q32)*64   + ((vsl ^ kx)*8)];
          oB = __builtin_amdgcn_mfma_f32_32x32x16_bf16(pa, vf1, oB, 0,0,0);
        }
        __builtin_amdgcn_s_setprio(0);
      }
    }

    if (kt < 16){
      writeT(cur ^ 1);
      __syncthreads();
    }
  }

  float rs_tot = rs + __shfl_xor(rs, 32);
  #pragma unroll
  for (int e = 0; e < 16; e++){
    int rowr = (e & 3) + 8*(e >> 2) + 4*hi;
    int q = q0w + rowr;
    if (q > 1024) continue;
    float inv = 1.0f / __shfl(rs_tot, rowr);
    size_t base = (size_t)(bN + q)*CD + h*DHD + q32;
    glob[base]      = f2bf(oA[e] * inv);
    glob[base + 32] = f2bf(oB[e] * inv);
  }
}

// ---------------- Depthwise 3x3 SAME conv, 4 outputs/thread ----------------
__global__ __launch_bounds__(512) void dwconv(
    const short* __restrict__ xb, const float* __restrict__ w, short* __restrict__ out)
{
  const int c = threadIdx.x;
  const int xx = blockIdx.x & 31;
  const int yg = (blockIdx.x >> 5) & 7;
  const int b  = blockIdx.x >> 8;
  const int y0 = yg << 2;
  float acc[4] = {0.f,0.f,0.f,0.f};
  #pragma unroll
  for (int dx = -1; dx <= 1; dx++){
    int x2 = xx + dx;
    if (x2 < 0 || x2 > 31) continue;
    float col[6];
    #pragma unroll
    for (int r = 0; r < 6; r++){
      int row = y0 - 1 + r;
      col[r] = (row >= 0 && row < 32)
             ? bf2f(xb[((size_t)(b*NT + 1 + row*32 + x2))*CD + c]) : 0.f;
    }
    float w0 = w[(0*3+dx+1)*CD + c];
    float w1 = w[(1*3+dx+1)*CD + c];
    float w2 = w[(2*3+dx+1)*CD + c];
    #pragma unroll
    for (int o = 0; o < 4; o++)
      acc[o] += col[o]*w0 + col[o+1]*w1 + col[o+2]*w2;
  }
  #pragma unroll
  for (int o = 0; o < 4; o++)
    out[((size_t)(b*HW + (y0+o)*32 + xx))*CD + c] = f2bf(acc[o]);
}

// ---------------- merged GN apply for both branches (bf16 in) ----------------
__global__ __launch_bounds__(512) void gn_apply2(
    const short* __restrict__ mmL, const short* __restrict__ mmF,
    const float* __restrict__ totL, const float* __restrict__ totF,
    const float* __restrict__ gL, const float* __restrict__ bL,
    const float* __restrict__ gF, const float* __restrict__ bF,
    short* __restrict__ loc, short* __restrict__ fr,
    float* __restrict__ colsumL, float* __restrict__ colsumF)
{
  const int br = blockIdx.x >> 8;
  const int bi = blockIdx.x & 255;
  const int c = threadIdx.x;
  const int b = bi >> 5;
  const int p0 = (bi & 31) << 5;
  const short* mm = br ? mmF : mmL;
  const float* tot = br ? totF : totL;
  short* out = br ? fr : loc;
  float* colsum = br ? colsumF : colsumL;
  const float inv = 1.0f / ((float)HW * CD);
  const float mu = tot[b*2] * inv;
  const float rstd = rsqrtf(tot[b*2+1]*inv - mu*mu + 1e-5f);
  const float gc = (br ? gF : gL)[c], bc = (br ? bF : bL)[c];
  float s = 0.0f;
  for (int r = 0; r < 32; r++){
    int p = p0 + r;
    float v = bf2f(mm[((size_t)b*HW + p)*CD + c]);
    v = (v - mu) * rstd * gc + bc;
    if (br) v = gelu_exact(v);
    out[((size_t)(b*NT + 1 + p))*CD + c] = f2bf(v);
    s += v;
  }
  atomicAdd(&colsum[b*CD + c], s);
}

__global__ __launch_bounds__(512) void colmean_fin2(
    const float* __restrict__ colsumL, const float* __restrict__ colsumF,
    short* __restrict__ loc, short* __restrict__ fr)
{
  const int c = threadIdx.x;
  const int b = blockIdx.x & 7;
  if (blockIdx.x < 8) loc[((size_t)b*NT)*CD + c] = f2bf(colsumL[b*CD + c] * (1.0f/HW));
  else                fr [((size_t)b*NT)*CD + c] = f2bf(colsumF[b*CD + c] * (1.0f/HW));
}

// ---------------- FFT branch: 4 kernels, Hermitian-half U ----------------
__global__ __launch_bounds__(512) void fft_f1(
    const float* __restrict__ x, float* __restrict__ Ur, float* __restrict__ Ui)
{
  const int c = threadIdx.x;
  const int xx = blockIdx.x & 31;
  const int b = blockIdx.x >> 5;
  __shared__ float ct[32], st[32];
  if (c < 32){ float ang = 6.283185307179586f * c / 32.0f; ct[c] = cosf(ang); st[c] = sinf(ang); }
  __syncthreads();
  float v[32];
  #pragma unroll
  for (int y = 0; y < 32; y++) v[y] = x[((size_t)(b*NT + 1 + y*32 + xx))*CD + c];
  for (int ky = 0; ky <= 16; ky++){
    float sr = 0.f, si = 0.f;
    #pragma unroll
    for (int y = 0; y < 32; y++){
      int idx = (ky*y) & 31;
      sr += v[y]*ct[idx]; si -= v[y]*st[idx];
    }
    size_t o = ((size_t)((b*17+ky)*32+xx))*CD + c;
    Ur[o] = sr; Ui[o] = si;
  }
}

__global__ __launch_bounds__(256) void fft_f2(
    const float* __restrict__ Ur, const float* __restrict__ Ui,
    const float* __restrict__ wr, const float* __restrict__ wi,
    float* __restrict__ Gr, float* __restrict__ Gi)
{
  const int c = (blockIdx.x & 1)*256 + threadIdx.x;
  const int t = blockIdx.x >> 1;
  const int ky = t % 17, b = t / 17;
  __shared__ float ct[32], st[32];
  if (threadIdx.x < 32){ float ang = 6.283185307179586f * threadIdx.x / 32.0f;
    ct[threadIdx.x] = cosf(ang); st[threadIdx.x] = sinf(ang); }
  __syncthreads();
  float ar[32], ai[32];
  #pragma unroll
  for (int kx = 0; kx < 32; kx++){ ar[kx] = 0.f; ai[kx] = 0.f; }
  #pragma unroll
  for (int xx = 0; xx < 32; xx++){
    size_t o = ((size_t)((b*17+ky)*32+xx))*CD + c;
    float ur = Ur[o], ui = Ui[o];
    #pragma unroll
    for (int kx = 0; kx < 32; kx++){
      int idx = (kx*xx) & 31;
      float cc = ct[idx], ss = st[idx];
      ar[kx] += ur*cc + ui*ss;
      ai[kx] += ui*cc - ur*ss;
    }
  }
  #pragma unroll
  for (int kx = 0; kx < FWD; kx++){
    size_t fo = ((size_t)(ky*FWD+kx))*CD + c;
    float fwr = wr[fo], fwi = wi[fo];
    size_t go = ((size_t)((b*17+kx)*32+ky))*CD + c;
    Gr[go] = ar[kx]*fwr - ai[kx]*fwi;
    Gi[go] = ar[kx]*fwi + ai[kx]*fwr;
  }
  if (ky >= 1 && ky <= 15){
    const int ky2 = 32 - ky;
    #pragma unroll
    for (int kx = 0; kx < FWD; kx++){
      int m = (32 - kx) & 31;
      size_t fo = ((size_t)(ky2*FWD+kx))*CD + c;
      float fwr = wr[fo], fwi = wi[fo];
      size_t go = ((size_t)((b*17+kx)*32+ky2))*CD + c;
      Gr[go] = ar[m]*fwr + ai[m]*fwi;
      Gi[go] = ar[m]*fwi - ai[m]*fwr;
    }
  }
}

__global__ __launch_bounds__(256) void fft_f3(
    const float* __restrict__ Gr, const float* __restrict__ Gi,
    float* __restrict__ Tr, float* __restrict__ Ti)
{
  const int c = (blockIdx.x & 1)*256 + threadIdx.x;
  const int t = blockIdx.x >> 1;
  const int kx = t % 17, b = t / 17;
  __shared__ float ct[32], st[32];
  if (threadIdx.x < 32){ float ang = 6.283185307179586f * threadIdx.x / 32.0f;
    ct[threadIdx.x] = cosf(ang); st[threadIdx.x] = sinf(ang); }
  __syncthreads();
  float tr[32], ti[32];
  #pragma unroll
  for (int y = 0; y < 32; y++){ tr[y] = 0.f; ti[y] = 0.f; }
  #pragma unroll
  for (int ky = 0; ky < 32; ky++){
    size_t go = ((size_t)((b*17+kx)*32+ky))*CD + c;
    float gr = Gr[go], gi = Gi[go];
    #pragma unroll
    for (int y = 0; y < 32; y++){
      int idx = (ky*y) & 31;
      float cc = ct[idx], ss = st[idx];
      tr[y] += gr*cc - gi*ss;
      ti[y] += gr*ss + gi*cc;
    }
  }
  #pragma unroll
  for (int y = 0; y < 32; y++){
    size_t to = ((size_t)((b*32+y)*17+kx))*CD + c;
    Tr[to] = tr[y]*(1.0f/32.0f);
    Ti[to] = ti[y]*(1.0f/32.0f);
  }
}

__global__ __launch_bounds__(512) void fft_f4(
    const float* __restrict__ Tr, const float* __restrict__ Ti, short* __restrict__ xe)
{
  const int c = threadIdx.x;
  const int y = blockIdx.x & 31;
  const int b = blockIdx.x >> 5;
  __shared__ float ct[32], st[32];
  if (c < 32){ float ang = 6.283185307179586f * c / 32.0f; ct[c] = cosf(ang); st[c] = sinf(ang); }
  __syncthreads();
  float tr[FWD], ti[FWD];
  #pragma unroll
  for (int kx = 0; kx < FWD; kx++){
    size_t o = ((size_t)((b*32+y)*17+kx))*CD + c;
    tr[kx] = Tr[o]; ti[kx] = Ti[o];
  }
  for (int x2 = 0; x2 < 32; x2++){
    float acc = tr[0] + ((x2 & 1) ? -tr[16] : tr[16]);
    #pragma unroll
    for (int k2 = 1; k2 < 16; k2++){
      int idx = (k2*x2) & 31;
      acc += 2.0f*(tr[k2]*ct[idx] - ti[k2]*st[idx]);
    }
    xe[((size_t)(b*HW + y*32 + x2))*CD + c] = f2bf(acc*(1.0f/32.0f));
  }
}

// ---------------- gate tail + fusion: one wave per token ----------------
__global__ __launch_bounds__(256) void gate_fuse(
    const short* __restrict__ h1, const float* __restrict__ gW2, const float* __restrict__ gb2,
    const short* __restrict__ glob, const short* __restrict__ loc, const short* __restrict__ fr,
    short* __restrict__ fused)
{
  const int token = blockIdx.x*4 + (threadIdx.x >> 6);
  const int lane = threadIdx.x & 63;
  if (token >= MTOK) return;
  float p0 = 0.f, p1 = 0.f, p2 = 0.f;
  #pragma unroll
  for (int i = 0; i < 6; i++){
    int idx = lane + i*64;
    float h = bf2f(h1[(size_t)token*384 + idx]);
    p0 += h * gW2[idx*3+0]; p1 += h * gW2[idx*3+1]; p2 += h * gW2[idx*3+2];
  }
  #pragma unroll
  for (int o = 32; o > 0; o >>= 1){
    p0 += __shfl_xor(p0, o); p1 += __shfl_xor(p1, o); p2 += __shfl_xor(p2, o);
  }
  p0 += gb2[0]; p1 += gb2[1]; p2 += gb2[2];
  float mx = fmaxf(p0, fmaxf(p1, p2));
  float e0 = __expf(p0-mx), e1 = __expf(p1-mx), e2 = __expf(p2-mx);
  float inv = 1.0f/(e0+e1+e2);
  float g0 = e0*inv, g1 = e1*inv, g2 = e2*inv;
  #pragma unroll
  for (int i = 0; i < 8; i++){
    size_t o2 = (size_t)token*CD + lane + i*64;
    fused[o2] = f2bf(g0*bf2f(glob[o2]) + g1*bf2f(loc[o2]) + g2*bf2f(fr[o2]));
  }
}

extern "C" void kernel_launch(void* const* d_in, const int* in_sizes, int n_in,
                              void* d_out, int out_size, void* d_ws, size_t ws_size,
                              hipStream_t stream)
{
  const float* x     = (const float*)d_in[0];
  const float* Wq    = (const float*)d_in[1];
  const float* Wk    = (const float*)d_in[2];
  const float* Wv    = (const float*)d_in[3];
  const float* dw_w  = (const float*)d_in[4];
  const float* pw_w  = (const float*)d_in[5];
  const float* ln_g  = (const float*)d_in[6];
  const float* ln_b  = (const float*)d_in[7];
  const float* fr_wr = (const float*)d_in[8];
  const float* fr_wi = (const float*)d_in[9];
  const float* fr_pw = (const float*)d_in[10];
  const float* fr_g  = (const float*)d_in[11];
  const float* fr_b  = (const float*)d_in[12];
  const float* g_W1  = (const float*)d_in[13];
  const float* g_b1  = (const float*)d_in[14];
  const float* g_W2  = (const float*)d_in[15];
  const float* g_b2  = (const float*)d_in[16];
  const float* Wp    = (const float*)d_in[17];
  const float* bp    = (const float*)d_in[18];

  float* ws = (float*)d_ws;
  float* scrA = ws;
  float* scrB = scrA + 8388608;
  float* stats = scrB + 4456448;
  float* totL    = stats;
  float* totF    = stats + 16;
  float* colsumL = stats + 64;
  float* colsumF = stats + 64 + 4096;

  const size_t RPAD = 8448;
  short* glob  = (short*)(stats + 16384);
  short* loc   = glob  + RPAD*CD;
  short* fr    = loc   + RPAD*CD;
  short* actbL = fr    + RPAD*CD;
  short* actbF = actbL + RPAD*CD;
  short* fused = actbL;
  short* qkvb  = actbF + RPAD*CD;
  short* xb    = qkvb + (size_t)MPAD*QKS;
  short* wqkvt = xb + (size_t)MPAD*CD;
  short* pwt   = wqkvt + 1536*512;
  short* frpwt = pwt + 512*512;
  short* gw1t  = frpwt + 512*512;
  short* wpt   = gw1t + 384*1536;
  short* mmL = (short*)scrA;
  short* mmF = mmL + (size_t)8192*CD;

  hipMemsetAsync(stats, 0, (64 + 2*4096)*sizeof(float), stream);
  wconv_all<<<2112, 256, 0, stream>>>(Wq, Wk, Wv, pw_w, fr_pw, g_W1, Wp,
                                      wqkvt, pwt, frpwt, gw1t, wpt);
  x2bf<<<2080, 256, 0, stream>>>(x, xb);

  // ---- branch 1: packed QKV (bf16, swizzled) + 32x32 flash attention ----
  gemm_bf16<<<1560, 256, 0, stream>>>(xb, wqkvt, nullptr, qkvb, MPAD, 1536, 512, 4);
  attn_mfma32<<<576, 256, 0, stream>>>(qkvb, glob);

  // ---- independent producers: dwconv + FFT chain ----
  dwconv<<<BB*8*32, 512, 0, stream>>>(xb, dw_w, actbL);
  float* Ur = scrA;            float* Ui = scrA + 2228224;
  float* Gr = scrB;            float* Gi = scrB + 2228224;
  float* Tr = scrA;            float* Ti = scrA + 2228224;
  fft_f1<<<BB*32, 512, 0, stream>>>(x, Ur, Ui);
  fft_f2<<<BB*17*2, 256, 0, stream>>>(Ur, Ui, fr_wr, fr_wi, Gr, Gi);
  fft_f3<<<BB*17*2, 256, 0, stream>>>(Gr, Gi, Tr, Ti);
  fft_f4<<<BB*32, 512, 0, stream>>>(Tr, Ti, actbF);

  // ---- merged pointwise GEMMs (1024 blocks, XCD-swizzled, gload_lds) ----
  gemm_pw2<<<1024, 256, 0, stream>>>(actbL, pwt, actbF, frpwt, mmL, mmF, totL, totF);

  // ---- merged GN apply + cls rows ----
  gn_apply2<<<512, 512, 0, stream>>>(mmL, mmF, totL, totF, ln_g, ln_b, fr_g, fr_b,
                                     loc, fr, colsumL, colsumF);
  colmean_fin2<<<16, 512, 0, stream>>>(colsumL, colsumF, loc, fr);

  // ---- gate MLP + fusion + output projection ----
  gemm_gate<<<390, 256, 0, stream>>>(glob, loc, fr, gw1t, g_b1, (short*)scrB, MTOK);
  gate_fuse<<<2050, 256, 0, stream>>>((short*)scrB, g_W2, g_b2, glob, loc, fr, fused);
  gemm_bf16<<<520, 256, 0, stream>>>(fused, wpt, bp, d_out, MTOK, 512, 512, 1);
}

// Round 13
// 307.285 us; speedup vs baseline: 1.0566x; 1.0566x over previous
//
#include <hip/hip_runtime.h>
#include <math.h>

#define BB 8
#define NT 1025
#define CD 512
#define NH 8
#define DHD 64
#define HW 1024
#define FWD 17
#define MTOK 8200
#define MPAD 8320
#define QKS 1536

typedef __attribute__((ext_vector_type(8))) short short8;
typedef __attribute__((ext_vector_type(4))) float f32x4;
typedef __attribute__((ext_vector_type(16))) float f32x16;
typedef __attribute__((ext_vector_type(4))) unsigned u32x4;

__device__ __forceinline__ float gelu_exact(float x){
  return 0.5f * x * (1.0f + erff(x * 0.70710678118654752f));
}

__device__ __forceinline__ short f2bf(float f){
  unsigned u = __float_as_uint(f);
  unsigned r = (u + 0x7FFFu + ((u >> 16) & 1u)) >> 16;
  return (short)r;
}

__device__ __forceinline__ float bf2f(short s){
  unsigned u = ((unsigned)(unsigned short)s) << 16;
  return __uint_as_float(u);
}

__device__ __forceinline__ unsigned cvt_pk_bf16(float lo, float hi){
  unsigned r;
  asm volatile("v_cvt_pk_bf16_f32 %0, %1, %2" : "=v"(r) : "v"(lo), "v"(hi));
  return r;
}

// bijective XCD swizzle (m204)
__device__ __forceinline__ int xcd_logical(int phys, int n){
  int xcd = phys & 7, slot = phys >> 3;
  int q = n >> 3, r = n & 7;
  return xcd*q + (xcd < r ? xcd : r) + slot;
}

// ---------------- prep: weight transposes + x->bf16 + stats zero, ONE kernel --
__global__ __launch_bounds__(256) void prep_all(
    const float* __restrict__ Wq, const float* __restrict__ Wk, const float* __restrict__ Wv,
    const float* __restrict__ pw, const float* __restrict__ frpw,
    const float* __restrict__ gW1, const float* __restrict__ Wp,
    short* __restrict__ wqkvt, short* __restrict__ pwt, short* __restrict__ frpwt,
    short* __restrict__ gw1t, short* __restrict__ wpt,
    const float* __restrict__ x, short* __restrict__ xb, float* __restrict__ stats)
{
  const int t = blockIdx.x;
  if (t >= 4192){
    int i0 = (t - 4192)*1024 + threadIdx.x;
    #pragma unroll
    for (int j = 0; j < 4; j++){
      int i = i0 + j*256;
      if (i < 8256) stats[i] = 0.f;
    }
    return;
  }
  if (t >= 2112){
    size_t i = ((size_t)(t - 2112)*256 + threadIdx.x) * 8;
    if (i >= (size_t)MPAD*CD) return;
    size_t row = i >> 9;
    short8 o;
    if (row < MTOK){
      #pragma unroll
      for (int j = 0; j < 8; j++) o[j] = f2bf(x[i+j]);
    } else {
      #pragma unroll
      for (int j = 0; j < 8; j++) o[j] = 0;
    }
    *(short8*)(xb + i) = o;
    return;
  }
  const float* W; short* Wt; int K, N, idx; float scale = 1.0f;
  if      (t < 256) { W = Wq;   Wt = wqkvt;            K=512;  N=512; idx=t;       scale=0.125f; }
  else if (t < 512) { W = Wk;   Wt = wqkvt+512*512;    K=512;  N=512; idx=t-256; }
  else if (t < 768) { W = Wv;   Wt = wqkvt+1024*512;   K=512;  N=512; idx=t-512; }
  else if (t < 1024){ W = pw;   Wt = pwt;              K=512;  N=512; idx=t-768; }
  else if (t < 1280){ W = frpw; Wt = frpwt;            K=512;  N=512; idx=t-1024; }
  else if (t < 1856){ W = gW1;  Wt = gw1t;             K=1536; N=384; idx=t-1280; }
  else              { W = Wp;   Wt = wpt;              K=512;  N=512; idx=t-1856; }
  const int ntn = N >> 5;
  const int n0 = (idx % ntn) << 5, k0 = (idx / ntn) << 5;
  __shared__ float tl[32][33];
  const int tx = threadIdx.x & 31, ty = threadIdx.x >> 5;
  #pragma unroll
  for (int i = 0; i < 32; i += 8)
    tl[ty+i][tx] = W[(size_t)(k0+ty+i)*N + n0+tx];
  __syncthreads();
  #pragma unroll
  for (int i = 0; i < 32; i += 8)
    Wt[(size_t)(n0+ty+i)*K + k0+tx] = f2bf(tl[tx][ty+i] * scale);
}

// ======== single-buffer GEMM step macros (r10 core — best measured) ==========
#define GEMM_DECL                                                          \
  __shared__ short As[128*64];                                             \
  __shared__ short Bs[64*64];                                              \
  const int tid = threadIdx.x;                                             \
  const int lane = tid & 63, wv = tid >> 6;                                \
  const int lc = lane & 15, lg = lane >> 4;                                \
  f32x4 acc[2][4];                                                         \
  _Pragma("unroll")                                                        \
  for (int rt=0;rt<2;rt++)                                                 \
    _Pragma("unroll")                                                      \
    for (int ct=0;ct<4;ct++) acc[rt][ct] = (f32x4){0.f,0.f,0.f,0.f};

#define GEMM_STAGE(Aptr, Ka, k0a, Bptr, Kb, k0b)                           \
  __syncthreads();                                                         \
  _Pragma("unroll")                                                        \
  for (int p = 0; p < 4; p++){                                             \
    int c = tid + p*256;                                                   \
    int r = c >> 3, s = c & 7;                                             \
    short8 v = *(const short8*)((Aptr) + (size_t)(row0 + r)*(Ka) + (k0a) + s*8); \
    *(short8*)&As[r*64 + ((s ^ (r & 7))*8)] = v;                           \
  }                                                                        \
  _Pragma("unroll")                                                        \
  for (int p = 0; p < 2; p++){                                             \
    int c = tid + p*256;                                                   \
    int r = c >> 3, s = c & 7;                                             \
    short8 v = *(const short8*)((Bptr) + (size_t)(col0 + r)*(Kb) + (k0b) + s*8); \
    *(short8*)&Bs[r*64 + ((s ^ (r & 7))*8)] = v;                           \
  }                                                                        \
  __syncthreads();

#define GEMM_COMPUTE                                                       \
  _Pragma("unroll")                                                        \
  for (int ks = 0; ks < 2; ks++){                                          \
    short8 af[2], bfr[4];                                                  \
    _Pragma("unroll")                                                      \
    for (int rt = 0; rt < 2; rt++){                                        \
      int r = wv*32 + rt*16 + lc;                                          \
      af[rt] = *(const short8*)&As[r*64 + (((ks*4+lg) ^ (r & 7))*8)];      \
    }                                                                      \
    _Pragma("unroll")                                                      \
    for (int ct = 0; ct < 4; ct++){                                        \
      int r = ct*16 + lc;                                                  \
      bfr[ct] = *(const short8*)&Bs[r*64 + (((ks*4+lg) ^ (r & 7))*8)];     \
    }                                                                      \
    _Pragma("unroll")                                                      \
    for (int rt = 0; rt < 2; rt++)                                         \
      _Pragma("unroll")                                                    \
      for (int ct = 0; ct < 4; ct++)                                       \
        acc[rt][ct] = __builtin_amdgcn_mfma_f32_16x16x32_bf16(af[rt], bfr[ct], acc[rt][ct], 0,0,0); \
  }

// ---------------- MEGA GEMM: QKV + pwL + pwF in one dispatch (2584 blocks) ---
__global__ __launch_bounds__(256) void gemm_mega(
    const short* __restrict__ xb, const short* __restrict__ wqkvt, short* __restrict__ qkvb,
    const short* __restrict__ aL, const short* __restrict__ bL, short* __restrict__ cL,
    float* __restrict__ totL,
    const short* __restrict__ aF, const short* __restrict__ bF, short* __restrict__ cF,
    float* __restrict__ totF)
{
  const int l = xcd_logical(blockIdx.x, 2584);
  const short *A, *Bt; short* Cm; float* tot = nullptr;
  int N, row0, col0;
  if (l < 1560){
    A = xb; Bt = wqkvt; Cm = qkvb; N = 1536;
    row0 = (l / 24) * 128; col0 = (l % 24) * 64;
  } else if (l < 2072){
    int l2 = l - 1560;
    A = aL; Bt = bL; Cm = cL; tot = totL; N = 512;
    row0 = (l2 >> 3) * 128; col0 = (l2 & 7) * 64;
  } else {
    int l2 = l - 2072;
    A = aF; Bt = bF; Cm = cF; tot = totF; N = 512;
    row0 = (l2 >> 3) * 128; col0 = (l2 & 7) * 64;
  }
  const int K = 512;
  GEMM_DECL;
  for (int k0 = 0; k0 < K; k0 += 64){
    GEMM_STAGE(A, K, k0, Bt, K, k0);
    GEMM_COMPUTE;
  }
  float s1 = 0.f, s2 = 0.f;
  #pragma unroll
  for (int rt = 0; rt < 2; rt++)
    #pragma unroll
    for (int e = 0; e < 4; e++){
      int gr = row0 + wv*32 + rt*16 + lg*4 + e;
      #pragma unroll
      for (int ct = 0; ct < 4; ct++){
        int gc = col0 + ct*16 + lc;
        float v = acc[rt][ct][e];
        Cm[(size_t)gr*N + gc] = f2bf(v);
        s1 += v; s2 += v*v;
      }
    }
  if (tot){
    #pragma unroll
    for (int o = 32; o > 0; o >>= 1){ s1 += __shfl_xor(s1, o); s2 += __shfl_xor(s2, o); }
    if (lane == 0){
      atomicAdd(&tot[(row0>>10)*2],   s1);
      atomicAdd(&tot[(row0>>10)*2+1], s2);
    }
  }
}

// ---------------- final GEMM (520 blocks, XCD-swizzled) ----------------
__global__ __launch_bounds__(256) void gemm_final(
    const short* __restrict__ A, const short* __restrict__ Bt,
    const float* __restrict__ bias, float* __restrict__ Cm, int M)
{
  const int N = 512, K = 512;
  const int l = xcd_logical(blockIdx.x, gridDim.x);
  const int row0 = (l >> 3) * 128, col0 = (l & 7) * 64;
  GEMM_DECL;
  for (int k0 = 0; k0 < K; k0 += 64){
    GEMM_STAGE(A, K, k0, Bt, K, k0);
    GEMM_COMPUTE;
  }
  #pragma unroll
  for (int rt = 0; rt < 2; rt++)
    #pragma unroll
    for (int e = 0; e < 4; e++){
      int gr = row0 + wv*32 + rt*16 + lg*4 + e;
      if (gr >= M) continue;
      #pragma unroll
      for (int ct = 0; ct < 4; ct++){
        int gc = col0 + ct*16 + lc;
        Cm[(size_t)gr*N + gc] = acc[rt][ct][e] + bias[gc];
      }
    }
}

// ---------------- gate GEMM (390 blocks, XCD-swizzled, 3-source A) ----------
__global__ __launch_bounds__(256) void gemm_gate(
    const short* __restrict__ A0, const short* __restrict__ A1, const short* __restrict__ A2,
    const short* __restrict__ Bt, const float* __restrict__ bias, short* __restrict__ Cm,
    int M)
{
  const int N = 384, K = 1536;
  const int l = xcd_logical(blockIdx.x, gridDim.x);
  const int row0 = (l / 6) * 128, col0 = (l % 6) * 64;
  GEMM_DECL;
  for (int kt = 0; kt < 24; kt++){
    int k0 = kt * 64;
    const short* Asrc = (k0 < 512) ? A0 : (k0 < 1024 ? A1 : A2);
    const int kb = k0 & 511;
    GEMM_STAGE(Asrc, 512, kb, Bt, K, k0);
    GEMM_COMPUTE;
  }
  #pragma unroll
  for (int rt = 0; rt < 2; rt++)
    #pragma unroll
    for (int e = 0; e < 4; e++){
      int gr = row0 + wv*32 + rt*16 + lg*4 + e;
      if (gr >= M) continue;
      #pragma unroll
      for (int ct = 0; ct < 4; ct++){
        int gc = col0 + ct*16 + lc;
        float v = acc[rt][ct][e] + bias[gc];
        Cm[(size_t)gr*N + gc] = f2bf(gelu_exact(v));
      }
    }
}

// ---------------- Flash attention: 32x32 MFMA, swapped QK^T, in-reg softmax ---
__global__ __launch_bounds__(256) void attn_mfma32(
    const short* __restrict__ qkv, short* __restrict__ glob)
{
  const int bi = blockIdx.x;
  const int xcd = bi & 7;
  const int jj = bi >> 3;
  const int gq = jj / 9;
  const int qt = jj - gq*9;
  const int g  = xcd + 8*gq;
  const int h  = g & 7, b = g >> 3;

  const int tid = threadIdx.x;
  const int lane = tid & 63, wq = tid >> 6;
  const int q32 = lane & 31;
  const int hi  = lane >> 5;
  const int bN = b * NT;
  const int q0w = qt*128 + wq*32;

  __shared__ short Kl[2][64*64];
  __shared__ short Vl[2][64*64];

  short8 qf[4];
  {
    int qr = q0w + q32; if (qr > 1024) qr = 1024;
    const short* qp = qkv + (size_t)(bN + qr)*QKS + h*DHD + hi*8;
    qf[0] = *(const short8*)(qp);
    qf[1] = *(const short8*)(qp + 16);
    qf[2] = *(const short8*)(qp + 32);
    qf[3] = *(const short8*)(qp + 48);
  }

  f32x16 oA = {0.f,0.f,0.f,0.f,0.f,0.f,0.f,0.f,0.f,0.f,0.f,0.f,0.f,0.f,0.f,0.f};
  f32x16 oB = oA;
  float rs = 0.f;

  const int kc0 = tid;
  const int kc1 = tid + 256;
  const int vkey = tid & 63, vdg = tid >> 6;
  const short* kgbase = qkv + (size_t)bN*QKS + 512 + h*DHD;
  const short* vgbase = qkv + (size_t)bN*QKS + 1024 + h*DHD;

  short8 gk0, gk1, gv0, gv1;
  auto loadT = [&](int kt2){
    gk0 = *(const short8*)(kgbase + (size_t)(kt2*64 + (kc0>>3))*QKS + (kc0&7)*8);
    gk1 = *(const short8*)(kgbase + (size_t)(kt2*64 + (kc1>>3))*QKS + (kc1&7)*8);
    gv0 = *(const short8*)(vgbase + (size_t)(kt2*64 + vkey)*QKS + vdg*16);
    gv1 = *(const short8*)(vgbase + (size_t)(kt2*64 + vkey)*QKS + vdg*16 + 8);
  };
  auto writeT = [&](int buf){
    { int r = kc0>>3, sl = kc0&7;
      *(short8*)&Kl[buf][r*64 + (((sl) ^ (r&7))*8)] = gk0; }
    { int r = kc1>>3, sl = kc1&7;
      *(short8*)&Kl[buf][r*64 + (((sl) ^ (r&7))*8)] = gk1; }
    #pragma unroll
    for (int i2 = 0; i2 < 8; i2++){
      int d0 = vdg*16 + i2, d1 = vdg*16 + 8 + i2;
      Vl[buf][d0*64 + (((vkey>>3) ^ (d0&7))*8) + (vkey&7)] = gv0[i2];
      Vl[buf][d1*64 + (((vkey>>3) ^ (d1&7))*8) + (vkey&7)] = gv1[i2];
    }
  };

  loadT(0);
  writeT(0);
  __syncthreads();

  for (int kt = 0; kt < 17; kt++){
    const int cur = kt & 1;
    if (kt < 16) loadT(kt+1);

    #pragma unroll
    for (int ks = 0; ks < 2; ks++){
      f32x16 s = {0.f,0.f,0.f,0.f,0.f,0.f,0.f,0.f,0.f,0.f,0.f,0.f,0.f,0.f,0.f,0.f};
      const int krow = ks*32 + q32;
      const int kbase = krow*64;
      const int kx = q32 & 7;
      __builtin_amdgcn_s_setprio(1);
      #pragma unroll
      for (int kk = 0; kk < 4; kk++){
        short8 af = *(const short8*)&Kl[cur][kbase + (((2*kk+hi) ^ kx)*8)];
        s = __builtin_amdgcn_mfma_f32_32x32x16_bf16(af, qf[kk], s, 0,0,0);
      }
      __builtin_amdgcn_s_setprio(0);
      float p[16];
      if (kt == 16){
        #pragma unroll
        for (int e = 0; e < 16; e++){
          bool valid = (ks == 0) && (e == 0) && (hi == 0);
          p[e] = valid ? __expf(s[e]) : 0.f;
        }
      } else {
        #pragma unroll
        for (int e = 0; e < 16; e++) p[e] = __expf(s[e]);
      }
      #pragma unroll
      for (int e = 0; e < 16; e++) rs += p[e];
      unsigned pk[4][2];
      #pragma unroll
      for (int g2 = 0; g2 < 4; g2++){
        pk[g2][0] = cvt_pk_bf16(p[4*g2+0], p[4*g2+1]);
        pk[g2][1] = cvt_pk_bf16(p[4*g2+2], p[4*g2+3]);
      }
      #pragma unroll
      for (int kc = 0; kc < 2; kc++){
        unsigned e00 = pk[2*kc][0],   e01 = pk[2*kc][1];
        unsigned e10 = pk[2*kc+1][0], e11 = pk[2*kc+1][1];
        unsigned t00 = (unsigned)__shfl_xor((int)e00, 32);
        unsigned t01 = (unsigned)__shfl_xor((int)e01, 32);
        unsigned t10 = (unsigned)__shfl_xor((int)e10, 32);
        unsigned t11 = (unsigned)__shfl_xor((int)e11, 32);
        u32x4 pu;
        pu[0] = hi ? t10 : e00;
        pu[1] = hi ? t11 : e01;
        pu[2] = hi ? e10 : t00;
        pu[3] = hi ? e11 : t01;
        short8 pa = *(short8*)&pu;
        const int vsl = 4*ks + 2*kc + hi;
        __builtin_amdgcn_s_setprio(1);
        {
          short8 vf0 = *(const short8*)&Vl[cur][(q32)*64      + ((vsl ^ kx)*8)];
          oA = __builtin_amdgcn_mfma_f32_32x32x16_bf16(pa, vf0, oA, 0,0,0);
          short8 vf1 = *(const short8*)&Vl[cur][(32+q32)*64   + ((vsl ^ kx)*8)];
          oB = __builtin_amdgcn_mfma_f32_32x32x16_bf16(pa, vf1, oB, 0,0,0);
        }
        __builtin_amdgcn_s_setprio(0);
      }
    }

    if (kt < 16){
      writeT(cur ^ 1);
      __syncthreads();
    }
  }

  float rs_tot = rs + __shfl_xor(rs, 32);
  #pragma unroll
  for (int e = 0; e < 16; e++){
    int rowr = (e & 3) + 8*(e >> 2) + 4*hi;
    int q = q0w + rowr;
    if (q > 1024) continue;
    float inv = 1.0f / __shfl(rs_tot, rowr);
    size_t base = (size_t)(bN + q)*CD + h*DHD + q32;
    glob[base]      = f2bf(oA[e] * inv);
    glob[base + 32] = f2bf(oB[e] * inv);
  }
}

// ---------------- Depthwise 3x3 SAME conv, 4 outputs/thread ----------------
__global__ __launch_bounds__(512) void dwconv(
    const short* __restrict__ xb, const float* __restrict__ w, short* __restrict__ out)
{
  const int c = threadIdx.x;
  const int xx = blockIdx.x & 31;
  const int yg = (blockIdx.x >> 5) & 7;
  const int b  = blockIdx.x >> 8;
  const int y0 = yg << 2;
  float acc[4] = {0.f,0.f,0.f,0.f};
  #pragma unroll
  for (int dx = -1; dx <= 1; dx++){
    int x2 = xx + dx;
    if (x2 < 0 || x2 > 31) continue;
    float col[6];
    #pragma unroll
    for (int r = 0; r < 6; r++){
      int row = y0 - 1 + r;
      col[r] = (row >= 0 && row < 32)
             ? bf2f(xb[((size_t)(b*NT + 1 + row*32 + x2))*CD + c]) : 0.f;
    }
    float w0 = w[(0*3+dx+1)*CD + c];
    float w1 = w[(1*3+dx+1)*CD + c];
    float w2 = w[(2*3+dx+1)*CD + c];
    #pragma unroll
    for (int o = 0; o < 4; o++)
      acc[o] += col[o]*w0 + col[o+1]*w1 + col[o+2]*w2;
  }
  #pragma unroll
  for (int o = 0; o < 4; o++)
    out[((size_t)(b*HW + (y0+o)*32 + xx))*CD + c] = f2bf(acc[o]);
}

// ---------------- merged GN apply for both branches (bf16 in) ----------------
__global__ __launch_bounds__(512) void gn_apply2(
    const short* __restrict__ mmL, const short* __restrict__ mmF,
    const float* __restrict__ totL, const float* __restrict__ totF,
    const float* __restrict__ gL, const float* __restrict__ bL,
    const float* __restrict__ gF, const float* __restrict__ bF,
    short* __restrict__ loc, short* __restrict__ fr,
    float* __restrict__ colsumL, float* __restrict__ colsumF)
{
  const int br = blockIdx.x >> 8;
  const int bi = blockIdx.x & 255;
  const int c = threadIdx.x;
  const int b = bi >> 5;
  const int p0 = (bi & 31) << 5;
  const short* mm = br ? mmF : mmL;
  const float* tot = br ? totF : totL;
  short* out = br ? fr : loc;
  float* colsum = br ? colsumF : colsumL;
  const float inv = 1.0f / ((float)HW * CD);
  const float mu = tot[b*2] * inv;
  const float rstd = rsqrtf(tot[b*2+1]*inv - mu*mu + 1e-5f);
  const float gc = (br ? gF : gL)[c], bc = (br ? bF : bL)[c];
  float s = 0.0f;
  for (int r = 0; r < 32; r++){
    int p = p0 + r;
    float v = bf2f(mm[((size_t)b*HW + p)*CD + c]);
    v = (v - mu) * rstd * gc + bc;
    if (br) v = gelu_exact(v);
    out[((size_t)(b*NT + 1 + p))*CD + c] = f2bf(v);
    s += v;
  }
  atomicAdd(&colsum[b*CD + c], s);
}

__global__ __launch_bounds__(512) void colmean_fin2(
    const float* __restrict__ colsumL, const float* __restrict__ colsumF,
    short* __restrict__ loc, short* __restrict__ fr)
{
  const int c = threadIdx.x;
  const int b = blockIdx.x & 7;
  if (blockIdx.x < 8) loc[((size_t)b*NT)*CD + c] = f2bf(colsumL[b*CD + c] * (1.0f/HW));
  else                fr [((size_t)b*NT)*CD + c] = f2bf(colsumF[b*CD + c] * (1.0f/HW));
}

// ---------------- FFT branch: 4 kernels, Hermitian-half U ----------------
__global__ __launch_bounds__(512) void fft_f1(
    const float* __restrict__ x, float* __restrict__ Ur, float* __restrict__ Ui)
{
  const int c = threadIdx.x;
  const int xx = blockIdx.x & 31;
  const int b = blockIdx.x >> 5;
  __shared__ float ct[32], st[32];
  if (c < 32){ float ang = 6.283185307179586f * c / 32.0f; ct[c] = cosf(ang); st[c] = sinf(ang); }
  __syncthreads();
  float v[32];
  #pragma unroll
  for (int y = 0; y < 32; y++) v[y] = x[((size_t)(b*NT + 1 + y*32 + xx))*CD + c];
  for (int ky = 0; ky <= 16; ky++){
    float sr = 0.f, si = 0.f;
    #pragma unroll
    for (int y = 0; y < 32; y++){
      int idx = (ky*y) & 31;
      sr += v[y]*ct[idx]; si -= v[y]*st[idx];
    }
    size_t o = ((size_t)((b*17+ky)*32+xx))*CD + c;
    Ur[o] = sr; Ui[o] = si;
  }
}

__global__ __launch_bounds__(256) void fft_f2(
    const float* __restrict__ Ur, const float* __restrict__ Ui,
    const float* __restrict__ wr, const float* __restrict__ wi,
    float* __restrict__ Gr, float* __restrict__ Gi)
{
  const int c = (blockIdx.x & 1)*256 + threadIdx.x;
  const int t = blockIdx.x >> 1;
  const int ky = t % 17, b = t / 17;
  __shared__ float ct[32], st[32];
  if (threadIdx.x < 32){ float ang = 6.283185307179586f * threadIdx.x / 32.0f;
    ct[threadIdx.x] = cosf(ang); st[threadIdx.x] = sinf(ang); }
  __syncthreads();
  float ar[32], ai[32];
  #pragma unroll
  for (int kx = 0; kx < 32; kx++){ ar[kx] = 0.f; ai[kx] = 0.f; }
  #pragma unroll
  for (int xx = 0; xx < 32; xx++){
    size_t o = ((size_t)((b*17+ky)*32+xx))*CD + c;
    float ur = Ur[o], ui = Ui[o];
    #pragma unroll
    for (int kx = 0; kx < 32; kx++){
      int idx = (kx*xx) & 31;
      float cc = ct[idx], ss = st[idx];
      ar[kx] += ur*cc + ui*ss;
      ai[kx] += ui*cc - ur*ss;
    }
  }
  #pragma unroll
  for (int kx = 0; kx < FWD; kx++){
    size_t fo = ((size_t)(ky*FWD+kx))*CD + c;
    float fwr = wr[fo], fwi = wi[fo];
    size_t go = ((size_t)((b*17+kx)*32+ky))*CD + c;
    Gr[go] = ar[kx]*fwr - ai[kx]*fwi;
    Gi[go] = ar[kx]*fwi + ai[kx]*fwr;
  }
  if (ky >= 1 && ky <= 15){
    const int ky2 = 32 - ky;
    #pragma unroll
    for (int kx = 0; kx < FWD; kx++){
      int m = (32 - kx) & 31;
      size_t fo = ((size_t)(ky2*FWD+kx))*CD + c;
      float fwr = wr[fo], fwi = wi[fo];
      size_t go = ((size_t)((b*17+kx)*32+ky2))*CD + c;
      Gr[go] = ar[m]*fwr + ai[m]*fwi;
      Gi[go] = ar[m]*fwi - ai[m]*fwr;
    }
  }
}

__global__ __launch_bounds__(256) void fft_f3(
    const float* __restrict__ Gr, const float* __restrict__ Gi,
    float* __restrict__ Tr, float* __restrict__ Ti)
{
  const int c = (blockIdx.x & 1)*256 + threadIdx.x;
  const int t = blockIdx.x >> 1;
  const int kx = t % 17, b = t / 17;
  __shared__ float ct[32], st[32];
  if (threadIdx.x < 32){ float ang = 6.283185307179586f * threadIdx.x / 32.0f;
    ct[threadIdx.x] = cosf(ang); st[threadIdx.x] = sinf(ang); }
  __syncthreads();
  float tr[32], ti[32];
  #pragma unroll
  for (int y = 0; y < 32; y++){ tr[y] = 0.f; ti[y] = 0.f; }
  #pragma unroll
  for (int ky = 0; ky < 32; ky++){
    size_t go = ((size_t)((b*17+kx)*32+ky))*CD + c;
    float gr = Gr[go], gi = Gi[go];
    #pragma unroll
    for (int y = 0; y < 32; y++){
      int idx = (ky*y) & 31;
      float cc = ct[idx], ss = st[idx];
      tr[y] += gr*cc - gi*ss;
      ti[y] += gr*ss + gi*cc;
    }
  }
  #pragma unroll
  for (int y = 0; y < 32; y++){
    size_t to = ((size_t)((b*32+y)*17+kx))*CD + c;
    Tr[to] = tr[y]*(1.0f/32.0f);
    Ti[to] = ti[y]*(1.0f/32.0f);
  }
}

__global__ __launch_bounds__(512) void fft_f4(
    const float* __restrict__ Tr, const float* __restrict__ Ti, short* __restrict__ xe)
{
  const int c = threadIdx.x;
  const int y = blockIdx.x & 31;
  const int b = blockIdx.x >> 5;
  __shared__ float ct[32], st[32];
  if (c < 32){ float ang = 6.283185307179586f * c / 32.0f; ct[c] = cosf(ang); st[c] = sinf(ang); }
  __syncthreads();
  float tr[FWD], ti[FWD];
  #pragma unroll
  for (int kx = 0; kx < FWD; kx++){
    size_t o = ((size_t)((b*32+y)*17+kx))*CD + c;
    tr[kx] = Tr[o]; ti[kx] = Ti[o];
  }
  for (int x2 = 0; x2 < 32; x2++){
    float acc = tr[0] + ((x2 & 1) ? -tr[16] : tr[16]);
    #pragma unroll
    for (int k2 = 1; k2 < 16; k2++){
      int idx = (k2*x2) & 31;
      acc += 2.0f*(tr[k2]*ct[idx] - ti[k2]*st[idx]);
    }
    xe[((size_t)(b*HW + y*32 + x2))*CD + c] = f2bf(acc*(1.0f/32.0f));
  }
}

// ---------------- gate tail + fusion: one wave per token ----------------
__global__ __launch_bounds__(256) void gate_fuse(
    const short* __restrict__ h1, const float* __restrict__ gW2, const float* __restrict__ gb2,
    const short* __restrict__ glob, const short* __restrict__ loc, const short* __restrict__ fr,
    short* __restrict__ fused)
{
  const int token = blockIdx.x*4 + (threadIdx.x >> 6);
  const int lane = threadIdx.x & 63;
  if (token >= MTOK) return;
  float p0 = 0.f, p1 = 0.f, p2 = 0.f;
  #pragma unroll
  for (int i = 0; i < 6; i++){
    int idx = lane + i*64;
    float h = bf2f(h1[(size_t)token*384 + idx]);
    p0 += h * gW2[idx*3+0]; p1 += h * gW2[idx*3+1]; p2 += h * gW2[idx*3+2];
  }
  #pragma unroll
  for (int o = 32; o > 0; o >>= 1){
    p0 += __shfl_xor(p0, o); p1 += __shfl_xor(p1, o); p2 += __shfl_xor(p2, o);
  }
  p0 += gb2[0]; p1 += gb2[1]; p2 += gb2[2];
  float mx = fmaxf(p0, fmaxf(p1, p2));
  float e0 = __expf(p0-mx), e1 = __expf(p1-mx), e2 = __expf(p2-mx);
  float inv = 1.0f/(e0+e1+e2);
  float g0 = e0*inv, g1 = e1*inv, g2 = e2*inv;
  #pragma unroll
  for (int i = 0; i < 8; i++){
    size_t o2 = (size_t)token*CD + lane + i*64;
    fused[o2] = f2bf(g0*bf2f(glob[o2]) + g1*bf2f(loc[o2]) + g2*bf2f(fr[o2]));
  }
}

extern "C" void kernel_launch(void* const* d_in, const int* in_sizes, int n_in,
                              void* d_out, int out_size, void* d_ws, size_t ws_size,
                              hipStream_t stream)
{
  const float* x     = (const float*)d_in[0];
  const float* Wq    = (const float*)d_in[1];
  const float* Wk    = (const float*)d_in[2];
  const float* Wv    = (const float*)d_in[3];
  const float* dw_w  = (const float*)d_in[4];
  const float* pw_w  = (const float*)d_in[5];
  const float* ln_g  = (const float*)d_in[6];
  const float* ln_b  = (const float*)d_in[7];
  const float* fr_wr = (const float*)d_in[8];
  const float* fr_wi = (const float*)d_in[9];
  const float* fr_pw = (const float*)d_in[10];
  const float* fr_g  = (const float*)d_in[11];
  const float* fr_b  = (const float*)d_in[12];
  const float* g_W1  = (const float*)d_in[13];
  const float* g_b1  = (const float*)d_in[14];
  const float* g_W2  = (const float*)d_in[15];
  const float* g_b2  = (const float*)d_in[16];
  const float* Wp    = (const float*)d_in[17];
  const float* bp    = (const float*)d_in[18];

  float* ws = (float*)d_ws;
  float* scrA = ws;                               // FFT U/T; then mmL/mmF bf16
  float* scrB = scrA + 8388608;                   // FFT G, h1-bf16
  float* stats = scrB + 4456448;
  float* totL    = stats;
  float* totF    = stats + 16;
  float* colsumL = stats + 64;
  float* colsumF = stats + 64 + 4096;

  const size_t RPAD = 8448;
  short* glob  = (short*)(stats + 16384);
  short* loc   = glob  + RPAD*CD;
  short* fr    = loc   + RPAD*CD;
  short* actbL = fr    + RPAD*CD;
  short* actbF = actbL + RPAD*CD;
  short* fused = actbL;
  short* qkvb  = actbF + RPAD*CD;
  short* xb    = qkvb + (size_t)MPAD*QKS;
  short* wqkvt = xb + (size_t)MPAD*CD;
  short* pwt   = wqkvt + 1536*512;
  short* frpwt = pwt + 512*512;
  short* gw1t  = frpwt + 512*512;
  short* wpt   = gw1t + 384*1536;
  short* mmL = (short*)scrA;
  short* mmF = mmL + (size_t)8192*CD;

  // ---- prep: weights + x->bf16 + stats zero (one dispatch) ----
  prep_all<<<4201, 256, 0, stream>>>(Wq, Wk, Wv, pw_w, fr_pw, g_W1, Wp,
                                     wqkvt, pwt, frpwt, gw1t, wpt, x, xb, stats);

  // ---- independent producers first: dwconv + FFT chain ----
  dwconv<<<BB*8*32, 512, 0, stream>>>(xb, dw_w, actbL);
  float* Ur = scrA;            float* Ui = scrA + 2228224;
  float* Gr = scrB;            float* Gi = scrB + 2228224;
  float* Tr = scrA;            float* Ti = scrA + 2228224;
  fft_f1<<<BB*32, 512, 0, stream>>>(x, Ur, Ui);
  fft_f2<<<BB*17*2, 256, 0, stream>>>(Ur, Ui, fr_wr, fr_wi, Gr, Gi);
  fft_f3<<<BB*17*2, 256, 0, stream>>>(Gr, Gi, Tr, Ti);
  fft_f4<<<BB*32, 512, 0, stream>>>(Tr, Ti, actbF);

  // ---- MEGA GEMM: QKV + pwL + pwF (2584 blocks, XCD-swizzled) ----
  gemm_mega<<<2584, 256, 0, stream>>>(xb, wqkvt, qkvb,
                                      actbL, pwt, mmL, totL,
                                      actbF, frpwt, mmF, totF);

  // ---- attention (needs qkvb) ----
  attn_mfma32<<<576, 256, 0, stream>>>(qkvb, glob);

  // ---- merged GN apply + cls rows ----
  gn_apply2<<<512, 512, 0, stream>>>(mmL, mmF, totL, totF, ln_g, ln_b, fr_g, fr_b,
                                     loc, fr, colsumL, colsumF);
  colmean_fin2<<<16, 512, 0, stream>>>(colsumL, colsumF, loc, fr);

  // ---- gate MLP + fusion + output projection ----
  gemm_gate<<<390, 256, 0, stream>>>(glob, loc, fr, gw1t, g_b1, (short*)scrB, MTOK);
  gate_fuse<<<2050, 256, 0, stream>>>((short*)scrB, g_W2, g_b2, glob, loc, fr, fused);
  gemm_final<<<520, 256, 0, stream>>>(fused, wpt, bp, (float*)d_out, MTOK);
}

// Round 14
// 266.003 us; speedup vs baseline: 1.2205x; 1.1552x over previous
//
#include <hip/hip_runtime.h>
#include <math.h>

#define BB 8
#define NT 1025
#define CD 512
#define NH 8
#define DHD 64
#define HW 1024
#define FWD 17
#define MTOK 8200
#define MPAD 8320
#define QKS 1536

typedef __attribute__((ext_vector_type(8))) short short8;
typedef __attribute__((ext_vector_type(4))) float f32x4;
typedef __attribute__((ext_vector_type(16))) float f32x16;
typedef __attribute__((ext_vector_type(4))) unsigned u32x4;

__device__ __forceinline__ float gelu_exact(float x){
  return 0.5f * x * (1.0f + erff(x * 0.70710678118654752f));
}

__device__ __forceinline__ short f2bf(float f){
  unsigned u = __float_as_uint(f);
  unsigned r = (u + 0x7FFFu + ((u >> 16) & 1u)) >> 16;
  return (short)r;
}

__device__ __forceinline__ float bf2f(short s){
  unsigned u = ((unsigned)(unsigned short)s) << 16;
  return __uint_as_float(u);
}

__device__ __forceinline__ unsigned cvt_pk_bf16(float lo, float hi){
  unsigned r;
  asm volatile("v_cvt_pk_bf16_f32 %0, %1, %2" : "=v"(r) : "v"(lo), "v"(hi));
  return r;
}

// bijective XCD swizzle (m204)
__device__ __forceinline__ int xcd_logical(int phys, int n){
  int xcd = phys & 7, slot = phys >> 3;
  int q = n >> 3, r = n & 7;
  return xcd*q + (xcd < r ? xcd : r) + slot;
}

// ---------------- prep: weight transposes + x->bf16 + stats zero, ONE kernel --
__global__ __launch_bounds__(256) void prep_all(
    const float* __restrict__ Wq, const float* __restrict__ Wk, const float* __restrict__ Wv,
    const float* __restrict__ pw, const float* __restrict__ frpw,
    const float* __restrict__ gW1, const float* __restrict__ Wp,
    short* __restrict__ wqkvt, short* __restrict__ pwt, short* __restrict__ frpwt,
    short* __restrict__ gw1t, short* __restrict__ wpt,
    const float* __restrict__ x, short* __restrict__ xb, float* __restrict__ stats)
{
  const int t = blockIdx.x;
  if (t >= 4192){
    int i0 = (t - 4192)*1024 + threadIdx.x;
    #pragma unroll
    for (int j = 0; j < 4; j++){
      int i = i0 + j*256;
      if (i < 8256) stats[i] = 0.f;
    }
    return;
  }
  if (t >= 2112){
    size_t i = ((size_t)(t - 2112)*256 + threadIdx.x) * 8;
    if (i >= (size_t)MPAD*CD) return;
    size_t row = i >> 9;
    short8 o;
    if (row < MTOK){
      #pragma unroll
      for (int j = 0; j < 8; j++) o[j] = f2bf(x[i+j]);
    } else {
      #pragma unroll
      for (int j = 0; j < 8; j++) o[j] = 0;
    }
    *(short8*)(xb + i) = o;
    return;
  }
  const float* W; short* Wt; int K, N, idx; float scale = 1.0f;
  if      (t < 256) { W = Wq;   Wt = wqkvt;            K=512;  N=512; idx=t;       scale=0.125f; }
  else if (t < 512) { W = Wk;   Wt = wqkvt+512*512;    K=512;  N=512; idx=t-256; }
  else if (t < 768) { W = Wv;   Wt = wqkvt+1024*512;   K=512;  N=512; idx=t-512; }
  else if (t < 1024){ W = pw;   Wt = pwt;              K=512;  N=512; idx=t-768; }
  else if (t < 1280){ W = frpw; Wt = frpwt;            K=512;  N=512; idx=t-1024; }
  else if (t < 1856){ W = gW1;  Wt = gw1t;             K=1536; N=384; idx=t-1280; }
  else              { W = Wp;   Wt = wpt;              K=512;  N=512; idx=t-1856; }
  const int ntn = N >> 5;
  const int n0 = (idx % ntn) << 5, k0 = (idx / ntn) << 5;
  __shared__ float tl[32][33];
  const int tx = threadIdx.x & 31, ty = threadIdx.x >> 5;
  #pragma unroll
  for (int i = 0; i < 32; i += 8)
    tl[ty+i][tx] = W[(size_t)(k0+ty+i)*N + n0+tx];
  __syncthreads();
  #pragma unroll
  for (int i = 0; i < 32; i += 8)
    Wt[(size_t)(n0+ty+i)*K + k0+tx] = f2bf(tl[tx][ty+i] * scale);
}

// ======== 128x64 single-buffer GEMM macros (gate / final) ==========
#define GEMM_DECL                                                          \
  __shared__ short As[128*64];                                             \
  __shared__ short Bs[64*64];                                              \
  const int tid = threadIdx.x;                                             \
  const int lane = tid & 63, wv = tid >> 6;                                \
  const int lc = lane & 15, lg = lane >> 4;                                \
  f32x4 acc[2][4];                                                         \
  _Pragma("unroll")                                                        \
  for (int rt=0;rt<2;rt++)                                                 \
    _Pragma("unroll")                                                      \
    for (int ct=0;ct<4;ct++) acc[rt][ct] = (f32x4){0.f,0.f,0.f,0.f};

#define GEMM_STAGE(Aptr, Ka, k0a, Bptr, Kb, k0b)                           \
  __syncthreads();                                                         \
  _Pragma("unroll")                                                        \
  for (int p = 0; p < 4; p++){                                             \
    int c = tid + p*256;                                                   \
    int r = c >> 3, s = c & 7;                                             \
    short8 v = *(const short8*)((Aptr) + (size_t)(row0 + r)*(Ka) + (k0a) + s*8); \
    *(short8*)&As[r*64 + ((s ^ (r & 7))*8)] = v;                           \
  }                                                                        \
  _Pragma("unroll")                                                        \
  for (int p = 0; p < 2; p++){                                             \
    int c = tid + p*256;                                                   \
    int r = c >> 3, s = c & 7;                                             \
    short8 v = *(const short8*)((Bptr) + (size_t)(col0 + r)*(Kb) + (k0b) + s*8); \
    *(short8*)&Bs[r*64 + ((s ^ (r & 7))*8)] = v;                           \
  }                                                                        \
  __syncthreads();

#define GEMM_COMPUTE                                                       \
  _Pragma("unroll")                                                        \
  for (int ks = 0; ks < 2; ks++){                                          \
    short8 af[2], bfr[4];                                                  \
    _Pragma("unroll")                                                      \
    for (int rt = 0; rt < 2; rt++){                                        \
      int r = wv*32 + rt*16 + lc;                                          \
      af[rt] = *(const short8*)&As[r*64 + (((ks*4+lg) ^ (r & 7))*8)];      \
    }                                                                      \
    _Pragma("unroll")                                                      \
    for (int ct = 0; ct < 4; ct++){                                        \
      int r = ct*16 + lc;                                                  \
      bfr[ct] = *(const short8*)&Bs[r*64 + (((ks*4+lg) ^ (r & 7))*8)];     \
    }                                                                      \
    _Pragma("unroll")                                                      \
    for (int rt = 0; rt < 2; rt++)                                         \
      _Pragma("unroll")                                                    \
      for (int ct = 0; ct < 4; ct++)                                       \
        acc[rt][ct] = __builtin_amdgcn_mfma_f32_16x16x32_bf16(af[rt], bfr[ct], acc[rt][ct], 0,0,0); \
  }

// ---------------- MEGA GEMM: 128x128 tile; QKV + pwL + pwF (1292 blocks) -----
__global__ __launch_bounds__(256) void gemm_mega(
    const short* __restrict__ xb, const short* __restrict__ wqkvt, short* __restrict__ qkvb,
    const short* __restrict__ aL, const short* __restrict__ bL, short* __restrict__ cL,
    float* __restrict__ totL,
    const short* __restrict__ aF, const short* __restrict__ bF, short* __restrict__ cF,
    float* __restrict__ totF)
{
  const int l = xcd_logical(blockIdx.x, 1292);
  const short *A, *Bt; short* Cm; float* tot = nullptr;
  int N, row0, col0;
  if (l < 780){
    A = xb; Bt = wqkvt; Cm = qkvb; N = 1536;
    row0 = (l / 12) * 128; col0 = (l % 12) * 128;
  } else if (l < 1036){
    int l2 = l - 780;
    A = aL; Bt = bL; Cm = cL; tot = totL; N = 512;
    row0 = (l2 >> 2) * 128; col0 = (l2 & 3) * 128;
  } else {
    int l2 = l - 1036;
    A = aF; Bt = bF; Cm = cF; tot = totF; N = 512;
    row0 = (l2 >> 2) * 128; col0 = (l2 & 3) * 128;
  }
  const int K = 512;

  __shared__ short As[128*64];
  __shared__ short Bs[128*64];
  const int tid = threadIdx.x;
  const int lane = tid & 63, wv = tid >> 6;
  const int lc = lane & 15, lg = lane >> 4;
  f32x4 acc[2][8];
  #pragma unroll
  for (int rt=0;rt<2;rt++)
    #pragma unroll
    for (int ct=0;ct<8;ct++) acc[rt][ct] = (f32x4){0.f,0.f,0.f,0.f};

  for (int k0 = 0; k0 < K; k0 += 64){
    __syncthreads();
    #pragma unroll
    for (int p = 0; p < 4; p++){
      int c = tid + p*256;
      int r = c >> 3, s = c & 7;
      short8 v = *(const short8*)(A + (size_t)(row0 + r)*K + k0 + s*8);
      *(short8*)&As[r*64 + ((s ^ (r & 7))*8)] = v;
    }
    #pragma unroll
    for (int p = 0; p < 4; p++){
      int c = tid + p*256;
      int r = c >> 3, s = c & 7;
      short8 v = *(const short8*)(Bt + (size_t)(col0 + r)*K + k0 + s*8);
      *(short8*)&Bs[r*64 + ((s ^ (r & 7))*8)] = v;
    }
    __syncthreads();
    #pragma unroll
    for (int ks = 0; ks < 2; ks++){
      short8 af[2], bfr[8];
      #pragma unroll
      for (int rt = 0; rt < 2; rt++){
        int r = wv*32 + rt*16 + lc;
        af[rt] = *(const short8*)&As[r*64 + (((ks*4+lg) ^ (r & 7))*8)];
      }
      #pragma unroll
      for (int ct = 0; ct < 8; ct++){
        int r = ct*16 + lc;
        bfr[ct] = *(const short8*)&Bs[r*64 + (((ks*4+lg) ^ (r & 7))*8)];
      }
      #pragma unroll
      for (int rt = 0; rt < 2; rt++)
        #pragma unroll
        for (int ct = 0; ct < 8; ct++)
          acc[rt][ct] = __builtin_amdgcn_mfma_f32_16x16x32_bf16(af[rt], bfr[ct], acc[rt][ct], 0,0,0);
    }
  }

  float s1 = 0.f, s2 = 0.f;
  #pragma unroll
  for (int rt = 0; rt < 2; rt++)
    #pragma unroll
    for (int e = 0; e < 4; e++){
      int gr = row0 + wv*32 + rt*16 + lg*4 + e;
      #pragma unroll
      for (int ct = 0; ct < 8; ct++){
        int gc = col0 + ct*16 + lc;
        float v = acc[rt][ct][e];
        Cm[(size_t)gr*N + gc] = f2bf(v);
        s1 += v; s2 += v*v;
      }
    }
  if (tot){
    #pragma unroll
    for (int o = 32; o > 0; o >>= 1){ s1 += __shfl_xor(s1, o); s2 += __shfl_xor(s2, o); }
    if (lane == 0){
      atomicAdd(&tot[(row0>>10)*2],   s1);
      atomicAdd(&tot[(row0>>10)*2+1], s2);
    }
  }
}

// ---------------- final GEMM (520 blocks, XCD-swizzled) ----------------
__global__ __launch_bounds__(256) void gemm_final(
    const short* __restrict__ A, const short* __restrict__ Bt,
    const float* __restrict__ bias, float* __restrict__ Cm, int M)
{
  const int N = 512, K = 512;
  const int l = xcd_logical(blockIdx.x, gridDim.x);
  const int row0 = (l >> 3) * 128, col0 = (l & 7) * 64;
  GEMM_DECL;
  for (int k0 = 0; k0 < K; k0 += 64){
    GEMM_STAGE(A, K, k0, Bt, K, k0);
    GEMM_COMPUTE;
  }
  #pragma unroll
  for (int rt = 0; rt < 2; rt++)
    #pragma unroll
    for (int e = 0; e < 4; e++){
      int gr = row0 + wv*32 + rt*16 + lg*4 + e;
      if (gr >= M) continue;
      #pragma unroll
      for (int ct = 0; ct < 4; ct++){
        int gc = col0 + ct*16 + lc;
        Cm[(size_t)gr*N + gc] = acc[rt][ct][e] + bias[gc];
      }
    }
}

// ---------------- gate GEMM (390 blocks, XCD-swizzled, 3-source A) ----------
__global__ __launch_bounds__(256) void gemm_gate(
    const short* __restrict__ A0, const short* __restrict__ A1, const short* __restrict__ A2,
    const short* __restrict__ Bt, const float* __restrict__ bias, short* __restrict__ Cm,
    int M)
{
  const int N = 384, K = 1536;
  const int l = xcd_logical(blockIdx.x, gridDim.x);
  const int row0 = (l / 6) * 128, col0 = (l % 6) * 64;
  GEMM_DECL;
  for (int kt = 0; kt < 24; kt++){
    int k0 = kt * 64;
    const short* Asrc = (k0 < 512) ? A0 : (k0 < 1024 ? A1 : A2);
    const int kb = k0 & 511;
    GEMM_STAGE(Asrc, 512, kb, Bt, K, k0);
    GEMM_COMPUTE;
  }
  #pragma unroll
  for (int rt = 0; rt < 2; rt++)
    #pragma unroll
    for (int e = 0; e < 4; e++){
      int gr = row0 + wv*32 + rt*16 + lg*4 + e;
      if (gr >= M) continue;
      #pragma unroll
      for (int ct = 0; ct < 4; ct++){
        int gc = col0 + ct*16 + lc;
        float v = acc[rt][ct][e] + bias[gc];
        Cm[(size_t)gr*N + gc] = f2bf(gelu_exact(v));
      }
    }
}

// ---------------- attention (blocks 0..575) + GN apply (blocks 576..1599) ----
__global__ __launch_bounds__(256) void attn_gn(
    const short* __restrict__ qkv, short* __restrict__ glob,
    const short* __restrict__ mmL, const short* __restrict__ mmF,
    const float* __restrict__ totL, const float* __restrict__ totF,
    const float* __restrict__ gL, const float* __restrict__ bL,
    const float* __restrict__ gF, const float* __restrict__ bF,
    short* __restrict__ loc, short* __restrict__ fr,
    float* __restrict__ colsumL, float* __restrict__ colsumF)
{
  __shared__ short Kl[2][64*64];
  __shared__ short Vl[2][64*64];

  if (blockIdx.x >= 576){
    // ---- GN path: 1024 blocks x 256 threads ----
    const int bi2 = blockIdx.x - 576;
    const int br = bi2 >> 9;
    const int rem = bi2 & 511;
    const int b = rem >> 6;
    const int sub = rem & 63;
    const int p0 = (sub >> 1) << 5;
    const int c = (sub & 1)*256 + threadIdx.x;
    const short* mm = br ? mmF : mmL;
    const float* tot = br ? totF : totL;
    short* out = br ? fr : loc;
    float* colsum = br ? colsumF : colsumL;
    const float inv = 1.0f / ((float)HW * CD);
    const float mu = tot[b*2] * inv;
    const float rstd = rsqrtf(tot[b*2+1]*inv - mu*mu + 1e-5f);
    const float gc = (br ? gF : gL)[c], bc = (br ? bF : bL)[c];
    float s = 0.0f;
    for (int r = 0; r < 32; r++){
      int p = p0 + r;
      float v = bf2f(mm[((size_t)b*HW + p)*CD + c]);
      v = (v - mu) * rstd * gc + bc;
      if (br) v = gelu_exact(v);
      out[((size_t)(b*NT + 1 + p))*CD + c] = f2bf(v);
      s += v;
    }
    atomicAdd(&colsum[b*CD + c], s);
    return;
  }

  // ---- attention path ----
  const int bi = blockIdx.x;
  const int xcd = bi & 7;
  const int jj = bi >> 3;
  const int gq = jj / 9;
  const int qt = jj - gq*9;
  const int g  = xcd + 8*gq;
  const int h  = g & 7, b = g >> 3;

  const int tid = threadIdx.x;
  const int lane = tid & 63, wq = tid >> 6;
  const int q32 = lane & 31;
  const int hi  = lane >> 5;
  const int bN = b * NT;
  const int q0w = qt*128 + wq*32;

  short8 qf[4];
  {
    int qr = q0w + q32; if (qr > 1024) qr = 1024;
    const short* qp = qkv + (size_t)(bN + qr)*QKS + h*DHD + hi*8;
    qf[0] = *(const short8*)(qp);
    qf[1] = *(const short8*)(qp + 16);
    qf[2] = *(const short8*)(qp + 32);
    qf[3] = *(const short8*)(qp + 48);
  }

  f32x16 oA = {0.f,0.f,0.f,0.f,0.f,0.f,0.f,0.f,0.f,0.f,0.f,0.f,0.f,0.f,0.f,0.f};
  f32x16 oB = oA;
  float rs = 0.f;

  const int kc0 = tid;
  const int kc1 = tid + 256;
  const int vkey = tid & 63, vdg = tid >> 6;
  const short* kgbase = qkv + (size_t)bN*QKS + 512 + h*DHD;
  const short* vgbase = qkv + (size_t)bN*QKS + 1024 + h*DHD;

  short8 gk0, gk1, gv0, gv1;
  auto loadT = [&](int kt2){
    gk0 = *(const short8*)(kgbase + (size_t)(kt2*64 + (kc0>>3))*QKS + (kc0&7)*8);
    gk1 = *(const short8*)(kgbase + (size_t)(kt2*64 + (kc1>>3))*QKS + (kc1&7)*8);
    gv0 = *(const short8*)(vgbase + (size_t)(kt2*64 + vkey)*QKS + vdg*16);
    gv1 = *(const short8*)(vgbase + (size_t)(kt2*64 + vkey)*QKS + vdg*16 + 8);
  };
  auto writeT = [&](int buf){
    { int r = kc0>>3, sl = kc0&7;
      *(short8*)&Kl[buf][r*64 + (((sl) ^ (r&7))*8)] = gk0; }
    { int r = kc1>>3, sl = kc1&7;
      *(short8*)&Kl[buf][r*64 + (((sl) ^ (r&7))*8)] = gk1; }
    #pragma unroll
    for (int i2 = 0; i2 < 8; i2++){
      int d0 = vdg*16 + i2, d1 = vdg*16 + 8 + i2;
      Vl[buf][d0*64 + (((vkey>>3) ^ (d0&7))*8) + (vkey&7)] = gv0[i2];
      Vl[buf][d1*64 + (((vkey>>3) ^ (d1&7))*8) + (vkey&7)] = gv1[i2];
    }
  };

  loadT(0);
  writeT(0);
  __syncthreads();

  for (int kt = 0; kt < 17; kt++){
    const int cur = kt & 1;
    if (kt < 16) loadT(kt+1);

    #pragma unroll
    for (int ks = 0; ks < 2; ks++){
      f32x16 s = {0.f,0.f,0.f,0.f,0.f,0.f,0.f,0.f,0.f,0.f,0.f,0.f,0.f,0.f,0.f,0.f};
      const int krow = ks*32 + q32;
      const int kbase = krow*64;
      const int kx = q32 & 7;
      __builtin_amdgcn_s_setprio(1);
      #pragma unroll
      for (int kk = 0; kk < 4; kk++){
        short8 af = *(const short8*)&Kl[cur][kbase + (((2*kk+hi) ^ kx)*8)];
        s = __builtin_amdgcn_mfma_f32_32x32x16_bf16(af, qf[kk], s, 0,0,0);
      }
      __builtin_amdgcn_s_setprio(0);
      float p[16];
      if (kt == 16){
        #pragma unroll
        for (int e = 0; e < 16; e++){
          bool valid = (ks == 0) && (e == 0) && (hi == 0);
          p[e] = valid ? __expf(s[e]) : 0.f;
        }
      } else {
        #pragma unroll
        for (int e = 0; e < 16; e++) p[e] = __expf(s[e]);
      }
      #pragma unroll
      for (int e = 0; e < 16; e++) rs += p[e];
      unsigned pk[4][2];
      #pragma unroll
      for (int g2 = 0; g2 < 4; g2++){
        pk[g2][0] = cvt_pk_bf16(p[4*g2+0], p[4*g2+1]);
        pk[g2][1] = cvt_pk_bf16(p[4*g2+2], p[4*g2+3]);
      }
      #pragma unroll
      for (int kc = 0; kc < 2; kc++){
        unsigned e00 = pk[2*kc][0],   e01 = pk[2*kc][1];
        unsigned e10 = pk[2*kc+1][0], e11 = pk[2*kc+1][1];
        unsigned t00 = (unsigned)__shfl_xor((int)e00, 32);
        unsigned t01 = (unsigned)__shfl_xor((int)e01, 32);
        unsigned t10 = (unsigned)__shfl_xor((int)e10, 32);
        unsigned t11 = (unsigned)__shfl_xor((int)e11, 32);
        u32x4 pu;
        pu[0] = hi ? t10 : e00;
        pu[1] = hi ? t11 : e01;
        pu[2] = hi ? e10 : t00;
        pu[3] = hi ? e11 : t01;
        short8 pa = *(short8*)&pu;
        const int vsl = 4*ks + 2*kc + hi;
        __builtin_amdgcn_s_setprio(1);
        {
          short8 vf0 = *(const short8*)&Vl[cur][(q32)*64      + ((vsl ^ kx)*8)];
          oA = __builtin_amdgcn_mfma_f32_32x32x16_bf16(pa, vf0, oA, 0,0,0);
          short8 vf1 = *(const short8*)&Vl[cur][(32+q32)*64   + ((vsl ^ kx)*8)];
          oB = __builtin_amdgcn_mfma_f32_32x32x16_bf16(pa, vf1, oB, 0,0,0);
        }
        __builtin_amdgcn_s_setprio(0);
      }
    }

    if (kt < 16){
      writeT(cur ^ 1);
      __syncthreads();
    }
  }

  float rs_tot = rs + __shfl_xor(rs, 32);
  #pragma unroll
  for (int e = 0; e < 16; e++){
    int rowr = (e & 3) + 8*(e >> 2) + 4*hi;
    int q = q0w + rowr;
    if (q > 1024) continue;
    float inv = 1.0f / __shfl(rs_tot, rowr);
    size_t base = (size_t)(bN + q)*CD + h*DHD + q32;
    glob[base]      = f2bf(oA[e] * inv);
    glob[base + 32] = f2bf(oB[e] * inv);
  }
}

// ---------------- dwconv (blocks 0..2047) + fft_f1 (blocks 2048..2303) -------
__global__ __launch_bounds__(512) void dw_fft1(
    const short* __restrict__ xb, const float* __restrict__ w, short* __restrict__ out,
    const float* __restrict__ x, float* __restrict__ Ur, float* __restrict__ Ui)
{
  __shared__ float ct[32], st[32];
  if (blockIdx.x >= 2048){
    const int bi = blockIdx.x - 2048;
    const int c = threadIdx.x;
    const int xx = bi & 31;
    const int b = bi >> 5;
    if (c < 32){ float ang = 6.283185307179586f * c / 32.0f; ct[c] = cosf(ang); st[c] = sinf(ang); }
    __syncthreads();
    float v[32];
    #pragma unroll
    for (int y = 0; y < 32; y++) v[y] = x[((size_t)(b*NT + 1 + y*32 + xx))*CD + c];
    for (int ky = 0; ky <= 16; ky++){
      float sr = 0.f, si = 0.f;
      #pragma unroll
      for (int y = 0; y < 32; y++){
        int idx = (ky*y) & 31;
        sr += v[y]*ct[idx]; si -= v[y]*st[idx];
      }
      size_t o = ((size_t)((b*17+ky)*32+xx))*CD + c;
      Ur[o] = sr; Ui[o] = si;
    }
    return;
  }
  const int c = threadIdx.x;
  const int xx = blockIdx.x & 31;
  const int yg = (blockIdx.x >> 5) & 7;
  const int b  = blockIdx.x >> 8;
  const int y0 = yg << 2;
  float acc[4] = {0.f,0.f,0.f,0.f};
  #pragma unroll
  for (int dx = -1; dx <= 1; dx++){
    int x2 = xx + dx;
    if (x2 < 0 || x2 > 31) continue;
    float col[6];
    #pragma unroll
    for (int r = 0; r < 6; r++){
      int row = y0 - 1 + r;
      col[r] = (row >= 0 && row < 32)
             ? bf2f(xb[((size_t)(b*NT + 1 + row*32 + x2))*CD + c]) : 0.f;
    }
    float w0 = w[(0*3+dx+1)*CD + c];
    float w1 = w[(1*3+dx+1)*CD + c];
    float w2 = w[(2*3+dx+1)*CD + c];
    #pragma unroll
    for (int o = 0; o < 4; o++)
      acc[o] += col[o]*w0 + col[o+1]*w1 + col[o+2]*w2;
  }
  #pragma unroll
  for (int o = 0; o < 4; o++)
    out[((size_t)(b*HW + (y0+o)*32 + xx))*CD + c] = f2bf(acc[o]);
}

__global__ __launch_bounds__(512) void colmean_fin2(
    const float* __restrict__ colsumL, const float* __restrict__ colsumF,
    short* __restrict__ loc, short* __restrict__ fr)
{
  const int c = threadIdx.x;
  const int b = blockIdx.x & 7;
  if (blockIdx.x < 8) loc[((size_t)b*NT)*CD + c] = f2bf(colsumL[b*CD + c] * (1.0f/HW));
  else                fr [((size_t)b*NT)*CD + c] = f2bf(colsumF[b*CD + c] * (1.0f/HW));
}

// ---------------- FFT f2/f3/f4 ----------------
__global__ __launch_bounds__(256) void fft_f2(
    const float* __restrict__ Ur, const float* __restrict__ Ui,
    const float* __restrict__ wr, const float* __restrict__ wi,
    float* __restrict__ Gr, float* __restrict__ Gi)
{
  const int c = (blockIdx.x & 1)*256 + threadIdx.x;
  const int t = blockIdx.x >> 1;
  const int ky = t % 17, b = t / 17;
  __shared__ float ct[32], st[32];
  if (threadIdx.x < 32){ float ang = 6.283185307179586f * threadIdx.x / 32.0f;
    ct[threadIdx.x] = cosf(ang); st[threadIdx.x] = sinf(ang); }
  __syncthreads();
  float ar[32], ai[32];
  #pragma unroll
  for (int kx = 0; kx < 32; kx++){ ar[kx] = 0.f; ai[kx] = 0.f; }
  #pragma unroll
  for (int xx = 0; xx < 32; xx++){
    size_t o = ((size_t)((b*17+ky)*32+xx))*CD + c;
    float ur = Ur[o], ui = Ui[o];
    #pragma unroll
    for (int kx = 0; kx < 32; kx++){
      int idx = (kx*xx) & 31;
      float cc = ct[idx], ss = st[idx];
      ar[kx] += ur*cc + ui*ss;
      ai[kx] += ui*cc - ur*ss;
    }
  }
  #pragma unroll
  for (int kx = 0; kx < FWD; kx++){
    size_t fo = ((size_t)(ky*FWD+kx))*CD + c;
    float fwr = wr[fo], fwi = wi[fo];
    size_t go = ((size_t)((b*17+kx)*32+ky))*CD + c;
    Gr[go] = ar[kx]*fwr - ai[kx]*fwi;
    Gi[go] = ar[kx]*fwi + ai[kx]*fwr;
  }
  if (ky >= 1 && ky <= 15){
    const int ky2 = 32 - ky;
    #pragma unroll
    for (int kx = 0; kx < FWD; kx++){
      int m = (32 - kx) & 31;
      size_t fo = ((size_t)(ky2*FWD+kx))*CD + c;
      float fwr = wr[fo], fwi = wi[fo];
      size_t go = ((size_t)((b*17+kx)*32+ky2))*CD + c;
      Gr[go] = ar[m]*fwr + ai[m]*fwi;
      Gi[go] = ar[m]*fwi - ai[m]*fwr;
    }
  }
}

__global__ __launch_bounds__(256) void fft_f3(
    const float* __restrict__ Gr, const float* __restrict__ Gi,
    float* __restrict__ Tr, float* __restrict__ Ti)
{
  const int c = (blockIdx.x & 1)*256 + threadIdx.x;
  const int t = blockIdx.x >> 1;
  const int kx = t % 17, b = t / 17;
  __shared__ float ct[32], st[32];
  if (threadIdx.x < 32){ float ang = 6.283185307179586f * threadIdx.x / 32.0f;
    ct[threadIdx.x] = cosf(ang); st[threadIdx.x] = sinf(ang); }
  __syncthreads();
  float tr[32], ti[32];
  #pragma unroll
  for (int y = 0; y < 32; y++){ tr[y] = 0.f; ti[y] = 0.f; }
  #pragma unroll
  for (int ky = 0; ky < 32; ky++){
    size_t go = ((size_t)((b*17+kx)*32+ky))*CD + c;
    float gr = Gr[go], gi = Gi[go];
    #pragma unroll
    for (int y = 0; y < 32; y++){
      int idx = (ky*y) & 31;
      float cc = ct[idx], ss = st[idx];
      tr[y] += gr*cc - gi*ss;
      ti[y] += gr*ss + gi*cc;
    }
  }
  #pragma unroll
  for (int y = 0; y < 32; y++){
    size_t to = ((size_t)((b*32+y)*17+kx))*CD + c;
    Tr[to] = tr[y]*(1.0f/32.0f);
    Ti[to] = ti[y]*(1.0f/32.0f);
  }
}

__global__ __launch_bounds__(512) void fft_f4(
    const float* __restrict__ Tr, const float* __restrict__ Ti, short* __restrict__ xe)
{
  const int c = threadIdx.x;
  const int y = blockIdx.x & 31;
  const int b = blockIdx.x >> 5;
  __shared__ float ct[32], st[32];
  if (c < 32){ float ang = 6.283185307179586f * c / 32.0f; ct[c] = cosf(ang); st[c] = sinf(ang); }
  __syncthreads();
  float tr[FWD], ti[FWD];
  #pragma unroll
  for (int kx = 0; kx < FWD; kx++){
    size_t o = ((size_t)((b*32+y)*17+kx))*CD + c;
    tr[kx] = Tr[o]; ti[kx] = Ti[o];
  }
  for (int x2 = 0; x2 < 32; x2++){
    float acc = tr[0] + ((x2 & 1) ? -tr[16] : tr[16]);
    #pragma unroll
    for (int k2 = 1; k2 < 16; k2++){
      int idx = (k2*x2) & 31;
      acc += 2.0f*(tr[k2]*ct[idx] - ti[k2]*st[idx]);
    }
    xe[((size_t)(b*HW + y*32 + x2))*CD + c] = f2bf(acc*(1.0f/32.0f));
  }
}

// ---------------- gate tail + fusion: one wave per token ----------------
__global__ __launch_bounds__(256) void gate_fuse(
    const short* __restrict__ h1, const float* __restrict__ gW2, const float* __restrict__ gb2,
    const short* __restrict__ glob, const short* __restrict__ loc, const short* __restrict__ fr,
    short* __restrict__ fused)
{
  const int token = blockIdx.x*4 + (threadIdx.x >> 6);
  const int lane = threadIdx.x & 63;
  if (token >= MTOK) return;
  float p0 = 0.f, p1 = 0.f, p2 = 0.f;
  #pragma unroll
  for (int i = 0; i < 6; i++){
    int idx = lane + i*64;
    float h = bf2f(h1[(size_t)token*384 + idx]);
    p0 += h * gW2[idx*3+0]; p1 += h * gW2[idx*3+1]; p2 += h * gW2[idx*3+2];
  }
  #pragma unroll
  for (int o = 32; o > 0; o >>= 1){
    p0 += __shfl_xor(p0, o); p1 += __shfl_xor(p1, o); p2 += __shfl_xor(p2, o);
  }
  p0 += gb2[0]; p1 += gb2[1]; p2 += gb2[2];
  float mx = fmaxf(p0, fmaxf(p1, p2));
  float e0 = __expf(p0-mx), e1 = __expf(p1-mx), e2 = __expf(p2-mx);
  float inv = 1.0f/(e0+e1+e2);
  float g0 = e0*inv, g1 = e1*inv, g2 = e2*inv;
  #pragma unroll
  for (int i = 0; i < 8; i++){
    size_t o2 = (size_t)token*CD + lane + i*64;
    fused[o2] = f2bf(g0*bf2f(glob[o2]) + g1*bf2f(loc[o2]) + g2*bf2f(fr[o2]));
  }
}

extern "C" void kernel_launch(void* const* d_in, const int* in_sizes, int n_in,
                              void* d_out, int out_size, void* d_ws, size_t ws_size,
                              hipStream_t stream)
{
  const float* x     = (const float*)d_in[0];
  const float* Wq    = (const float*)d_in[1];
  const float* Wk    = (const float*)d_in[2];
  const float* Wv    = (const float*)d_in[3];
  const float* dw_w  = (const float*)d_in[4];
  const float* pw_w  = (const float*)d_in[5];
  const float* ln_g  = (const float*)d_in[6];
  const float* ln_b  = (const float*)d_in[7];
  const float* fr_wr = (const float*)d_in[8];
  const float* fr_wi = (const float*)d_in[9];
  const float* fr_pw = (const float*)d_in[10];
  const float* fr_g  = (const float*)d_in[11];
  const float* fr_b  = (const float*)d_in[12];
  const float* g_W1  = (const float*)d_in[13];
  const float* g_b1  = (const float*)d_in[14];
  const float* g_W2  = (const float*)d_in[15];
  const float* g_b2  = (const float*)d_in[16];
  const float* Wp    = (const float*)d_in[17];
  const float* bp    = (const float*)d_in[18];

  float* ws = (float*)d_ws;
  float* scrA = ws;                               // FFT U/T; then mmL/mmF bf16
  float* scrB = scrA + 8388608;                   // FFT G, h1-bf16
  float* stats = scrB + 4456448;
  float* totL    = stats;
  float* totF    = stats + 16;
  float* colsumL = stats + 64;
  float* colsumF = stats + 64 + 4096;

  const size_t RPAD = 8448;
  short* glob  = (short*)(stats + 16384);
  short* loc   = glob  + RPAD*CD;
  short* fr    = loc   + RPAD*CD;
  short* actbL = fr    + RPAD*CD;
  short* actbF = actbL + RPAD*CD;
  short* fused = actbL;
  short* qkvb  = actbF + RPAD*CD;
  short* xb    = qkvb + (size_t)MPAD*QKS;
  short* wqkvt = xb + (size_t)MPAD*CD;
  short* pwt   = wqkvt + 1536*512;
  short* frpwt = pwt + 512*512;
  short* gw1t  = frpwt + 512*512;
  short* wpt   = gw1t + 384*1536;
  short* mmL = (short*)scrA;
  short* mmF = mmL + (size_t)8192*CD;

  // ---- prep: weights + x->bf16 + stats zero (one dispatch) ----
  prep_all<<<4201, 256, 0, stream>>>(Wq, Wk, Wv, pw_w, fr_pw, g_W1, Wp,
                                     wqkvt, pwt, frpwt, gw1t, wpt, x, xb, stats);

  // ---- independent producers: dwconv + fft_f1 merged; then f2..f4 ----
  float* Ur = scrA;            float* Ui = scrA + 2228224;
  float* Gr = scrB;            float* Gi = scrB + 2228224;
  float* Tr = scrA;            float* Ti = scrA + 2228224;
  dw_fft1<<<2304, 512, 0, stream>>>(xb, dw_w, actbL, x, Ur, Ui);
  fft_f2<<<BB*17*2, 256, 0, stream>>>(Ur, Ui, fr_wr, fr_wi, Gr, Gi);
  fft_f3<<<BB*17*2, 256, 0, stream>>>(Gr, Gi, Tr, Ti);
  fft_f4<<<BB*32, 512, 0, stream>>>(Tr, Ti, actbF);

  // ---- MEGA GEMM: QKV + pwL + pwF (1292 blocks, 128x128 tiles) ----
  gemm_mega<<<1292, 256, 0, stream>>>(xb, wqkvt, qkvb,
                                      actbL, pwt, mmL, totL,
                                      actbF, frpwt, mmF, totF);

  // ---- attention + GN apply merged (1600 blocks) ----
  attn_gn<<<1600, 256, 0, stream>>>(qkvb, glob, mmL, mmF, totL, totF,
                                    ln_g, ln_b, fr_g, fr_b,
                                    loc, fr, colsumL, colsumF);
  colmean_fin2<<<16, 512, 0, stream>>>(colsumL, colsumF, loc, fr);

  // ---- gate MLP + fusion + output projection ----
  gemm_gate<<<390, 256, 0, stream>>>(glob, loc, fr, gw1t, g_b1, (short*)scrB, MTOK);
  gate_fuse<<<2050, 256, 0, stream>>>((short*)scrB, g_W2, g_b2, glob, loc, fr, fused);
  gemm_final<<<520, 256, 0, stream>>>(fused, wpt, bp, (float*)d_out, MTOK);
}